// Round 4
// baseline (822.982 us; speedup 1.0000x reference)
//
#include <hip/hip_runtime.h>
#include <hip/hip_fp16.h>
#include <math.h>

#define S_LEN 2048
#define NHID  2048
#define D_HEAD 128
#define N_BH  32
#define EPS_Q 1e-8f

typedef _Float16 half8 __attribute__((ext_vector_type(8)));
typedef _Float16 half4 __attribute__((ext_vector_type(4)));
typedef float floatx4 __attribute__((ext_vector_type(4)));

// ---------------- kernel 1: per-(bh,chunk,d) partial sums of k and v ----------------
__global__ void means_kernel(const float* __restrict__ kk, const float* __restrict__ vv,
                             float* __restrict__ ksumP, float* __restrict__ vsumP) {
  int blk = blockIdx.x;            // 32 bh * 16 chunks of 128 rows
  int bh = blk >> 4, chunk = blk & 15;
  int b = bh >> 4, h = bh & 15;
  int t = threadIdx.x;
  int d4 = t & 31, sg = t >> 5;
  int s0 = chunk * 128;
  const long base = ((long)(b * S_LEN + s0)) * NHID + h * D_HEAD + d4 * 4;
  floatx4 ks = {0.f,0.f,0.f,0.f}, vs = {0.f,0.f,0.f,0.f};
  #pragma unroll 4
  for (int j = 0; j < 16; ++j) {
    long idx = base + (long)(sg * 16 + j) * NHID;
    ks += *(const floatx4*)(kk + idx);
    vs += *(const floatx4*)(vv + idx);
  }
  __shared__ floatx4 red[256];
  red[t] = ks; __syncthreads();
  if (t < 128) red[t] += red[t + 128]; __syncthreads();
  if (t < 64)  red[t] += red[t + 64];  __syncthreads();
  if (t < 32) *(floatx4*)(ksumP + (long)blk * 128 + t * 4) = red[t] + red[t + 32];
  __syncthreads();
  red[t] = vs; __syncthreads();
  if (t < 128) red[t] += red[t + 128]; __syncthreads();
  if (t < 64)  red[t] += red[t + 64];  __syncthreads();
  if (t < 32) *(floatx4*)(vsumP + (long)blk * 128 + t * 4) = red[t] + red[t + 32];
}

// ---------------- kernel 2 (fused): qquant | kquant | vprep ----------------
__global__ void prep_kernel(const float* __restrict__ q, const float* __restrict__ k,
                            const float* __restrict__ v,
                            const float* __restrict__ ksumP, const float* __restrict__ vsumP,
                            _Float16* __restrict__ qq, _Float16* __restrict__ kq,
                            _Float16* __restrict__ vt,
                            float* __restrict__ qscale, float* __restrict__ kscale,
                            float* __restrict__ vmean) {
  int blk = blockIdx.x;
  int t = threadIdx.x;
  int lane = t & 63, wid = t >> 6;
  __shared__ float wred[4];
  __shared__ __align__(16) _Float16 tile[64 * 136];
  int d4 = t & 31, sg = t >> 5;

  if (blk < 2048) {
    // ---- Q quant: 32 rows x 128 d
    int bh = blk >> 6, g = blk & 63;
    int b = bh >> 4, h = bh & 15;
    int s0 = g * 32;
    const long gbase = ((long)(b * S_LEN + s0)) * NHID + h * D_HEAD + d4 * 4;
    floatx4 vals[4]; float am = 0.f;
    #pragma unroll
    for (int j = 0; j < 4; ++j) {
      floatx4 x = *(const floatx4*)(q + gbase + (long)(sg + j * 8) * NHID);
      vals[j] = x;
      am = fmaxf(am, fmaxf(fmaxf(fabsf(x[0]), fabsf(x[1])), fmaxf(fabsf(x[2]), fabsf(x[3]))));
    }
    #pragma unroll
    for (int off = 1; off < 64; off <<= 1) am = fmaxf(am, __shfl_xor(am, off, 64));
    if (lane == 0) wred[wid] = am;
    __syncthreads();
    am = fmaxf(fmaxf(wred[0], wred[1]), fmaxf(wred[2], wred[3]));
    float scale = fmaxf(am / 127.0f, EPS_Q);
    if (t == 0) qscale[bh * 64 + g] = scale;
    float inv = 1.0f / scale;
    #pragma unroll
    for (int j = 0; j < 4; ++j) {
      half4 hv;
      #pragma unroll
      for (int c = 0; c < 4; ++c)
        hv[c] = (_Float16)fminf(fmaxf(rintf(vals[j][c] * inv), -127.f), 127.f);
      *(half4*)(qq + ((long)bh * S_LEN + s0 + sg + j * 8) * D_HEAD + d4 * 4) = hv;
    }
  } else if (blk < 3072) {
    // ---- K smooth+quant: 64 rows x 128 d
    int bb = blk - 2048;
    int bh = bb >> 5, g = bb & 31;
    int b = bh >> 4, h = bh & 15;
    int s0 = g * 64;
    floatx4 msum = {0.f,0.f,0.f,0.f};
    #pragma unroll
    for (int c = 0; c < 16; ++c)
      msum += *(const floatx4*)(ksumP + (long)(bh * 16 + c) * 128 + d4 * 4);
    floatx4 mean = msum * (1.0f / 2048.0f);
    const long gbase = ((long)(b * S_LEN + s0)) * NHID + h * D_HEAD + d4 * 4;
    floatx4 vals[8]; float am = 0.f;
    #pragma unroll
    for (int j = 0; j < 8; ++j) {
      floatx4 x = *(const floatx4*)(k + gbase + (long)(sg + j * 8) * NHID) - mean;
      vals[j] = x;
      am = fmaxf(am, fmaxf(fmaxf(fabsf(x[0]), fabsf(x[1])), fmaxf(fabsf(x[2]), fabsf(x[3]))));
    }
    #pragma unroll
    for (int off = 1; off < 64; off <<= 1) am = fmaxf(am, __shfl_xor(am, off, 64));
    if (lane == 0) wred[wid] = am;
    __syncthreads();
    am = fmaxf(fmaxf(wred[0], wred[1]), fmaxf(wred[2], wred[3]));
    float scale = fmaxf(am / 127.0f, EPS_Q);
    if (t == 0) kscale[bh * 32 + g] = scale;
    float inv = 1.0f / scale;
    #pragma unroll
    for (int j = 0; j < 8; ++j) {
      half4 hv;
      #pragma unroll
      for (int c = 0; c < 4; ++c)
        hv[c] = (_Float16)fminf(fmaxf(rintf(vals[j][c] * inv), -127.f), 127.f);
      *(half4*)(kq + ((long)bh * S_LEN + s0 + sg + j * 8) * D_HEAD + d4 * 4) = hv;
    }
  } else {
    // ---- V smooth -> fp16 transpose to [bh][d][s]
    int bb = blk - 3072;
    int bh = bb >> 5, st = bb & 31;
    int b = bh >> 4, h = bh & 15;
    int s0 = st * 64;
    floatx4 msum = {0.f,0.f,0.f,0.f};
    #pragma unroll
    for (int c = 0; c < 16; ++c)
      msum += *(const floatx4*)(vsumP + (long)(bh * 16 + c) * 128 + d4 * 4);
    floatx4 mean = msum * (1.0f / 2048.0f);
    if (st == 0 && sg == 0)
      *(floatx4*)(vmean + bh * D_HEAD + d4 * 4) = mean;
    const long gbase = ((long)(b * S_LEN + s0)) * NHID + h * D_HEAD + d4 * 4;
    #pragma unroll
    for (int j = 0; j < 8; ++j) {
      floatx4 x = *(const floatx4*)(v + gbase + (long)(sg + j * 8) * NHID) - mean;
      half4 hv = { (_Float16)x[0], (_Float16)x[1], (_Float16)x[2], (_Float16)x[3] };
      *(half4*)(tile + (sg + j * 8) * 136 + d4 * 4) = hv;
    }
    __syncthreads();
    int dr = t >> 1, sh = (t & 1) * 32;
    _Float16* dst = vt + ((long)bh * D_HEAD + dr) * S_LEN + s0 + sh;
    #pragma unroll
    for (int jo = 0; jo < 4; ++jo) {
      union { half8 v8; _Float16 h[8]; } u;
      #pragma unroll
      for (int ji = 0; ji < 8; ++ji) u.h[ji] = tile[(sh + jo * 8 + ji) * 136 + dr];
      *(half8*)(dst + jo * 8) = u.v8;
    }
  }
}

// ---------------- kernel 3: fused sliding-window attention ----------------
// v5: occupancy via GRID, not block size (v4's (512,4) spilled: VGPR 64,
// FETCH 990MB). Grid 1024 = 32 bh x 32 q-blocks of 64 rows; block = 256 thr
// = 4 waves = 2 q-strips x 2 key-halves; 32-key tiles so each half's K/V set
// is 16KB -> LDS 32KB (+768B) -> 4 blocks/CU x 4 waves = 16 waves/CU (2x v3).
// Per-wave datapath = v3 verbatim (swapped QK^T, in-reg P, defer-max) with
// nb in {0,1}; sacc/pa shrink so VGPR fits the (256,4)=128 budget (B=256
// budget semantics verified by r5 history: (256,3)->170, (256,4)->128).
// Key-half partials merged by v4's in-LDS combine (2 strips, fp32 O 32KB
// overlaying K/V).
__launch_bounds__(256, 4)
__global__ void attn_kernel(const _Float16* __restrict__ qq, const _Float16* __restrict__ kq,
                            const _Float16* __restrict__ vt,
                            const float* __restrict__ qscale, const float* __restrict__ kscale,
                            const float* __restrict__ vmean,
                            const int* __restrict__ wlp, const int* __restrict__ wrp,
                            float* __restrict__ out) {
  int bid = blockIdx.x;
  int xcd = bid & 7, rest = bid >> 3;    // 4 bh per XCD: K/V working set 4MB = L2-resident
  int bh = xcd * 4 + (rest & 3);
  int qb = rest >> 2;                    // 0..31
  int b = bh >> 4, h = bh & 15;
  int q0 = qb * 64;

  int wl = *wlp; if (wl < 0) wl = S_LEN;
  int wr = *wrp; if (wr < 0) wr = S_LEN;

  int t = threadIdx.x;
  int wv = t >> 6;
  int hf = wv >> 1;                      // key-half: waves 0,1 = lo; 2,3 = hi
  int wv2 = wv & 1;                      // q-strip within block
  int th = t & 127;                      // thread id within the 2-wave half
  int lane = t & 63;
  int ln = lane & 15;
  int qd = lane >> 4;

  int r0 = q0 + wv2 * 32;                // this wave's 32 q rows

  // LDS: per-half K/V staging sets (2 x 16KB); same 32KB reused as fp32 O-combine
  __shared__ __align__(16) char smem[32768];
  __shared__ float Mhi[2][32];
  __shared__ float Mmax[2][32];
  __shared__ float Lhi[2][32];
  _Float16* KlH = (_Float16*)(smem + hf * 16384);          // [key 32][d 128] swizzled
  _Float16* VlH = (_Float16*)(smem + hf * 16384 + 8192);   // [d 128][key 32] swizzled

  // Q fragments (MFMA B operand): lane (qd,ln) holds Q[r0+mh*16+ln][qd*8+j+32ks]
  half8 qa[2][4];
  #pragma unroll
  for (int mh = 0; mh < 2; ++mh) {
    const _Float16* qbase = qq + ((long)bh * S_LEN + r0 + mh * 16 + ln) * D_HEAD + qd * 8;
    #pragma unroll
    for (int ks = 0; ks < 4; ++ks)
      qa[mh][ks] = *(const half8*)(qbase + ks * 32);
  }
  float qs = qscale[bh * 64 + (r0 >> 5)];

  float mrow[2];                          // running max for q-row (ln) per half
  floatx4 lacc[2];                        // l in C-layout rows qd*4+r
  floatx4 oacc[2][8];
  #pragma unroll
  for (int mh = 0; mh < 2; ++mh) {
    mrow[mh] = -1e30f;
    #pragma unroll
    for (int r = 0; r < 4; ++r) lacc[mh][r] = 0.f;
    #pragma unroll
    for (int nd = 0; nd < 8; ++nd) oacc[mh][nd] = (floatx4){0.f,0.f,0.f,0.f};
  }

  int lo = q0 - wl; if (lo < 0) lo = 0;
  int hi = q0 + 63 + wr; if (hi > S_LEN - 1) hi = S_LEN - 1;
  int t_lo = lo >> 5, t_hi = hi >> 5;    // 32-key tiles
  int n = t_hi - t_lo + 1;
  int nh = (n + 1) >> 1;                 // lo half gets nh tiles, hi gets n-nh
  int sh0 = t_lo + hf * nh;              // this half's first tile
  int cl = hf ? (n - nh) : nh;           // this half's tile count (may be < nh)

  const float sm_scale = 0.08838834764831845f;  // 1/sqrt(128)
  const _Float16* kbase = kq + (long)bh * S_LEN * D_HEAD;
  const _Float16* vbase = vt + (long)bh * D_HEAD * S_LEN;
  const float* kscb = kscale + bh * 32;
  const half8 vones = { (_Float16)1, (_Float16)1, (_Float16)1, (_Float16)1,
                        (_Float16)1, (_Float16)1, (_Float16)1, (_Float16)1 };

  // register prefetch of this half's first tile (clamped if empty)
  half8 kpre[4], vpre[4];
  {
    int tp = sh0 > t_hi ? t_hi : sh0;
    int j0 = tp * 32;
    #pragma unroll
    for (int c = 0; c < 4; ++c) {
      int gc = th + c * 128;
      kpre[c] = *(const half8*)(kbase + (long)(j0 + (gc >> 4)) * D_HEAD + (gc & 15) * 8);
      vpre[c] = *(const half8*)(vbase + (long)(gc >> 2) * S_LEN + j0 + (gc & 3) * 8);
    }
  }

  for (int i = 0; i < nh; ++i) {
    int tt = sh0 + i;
    int j0 = tt * 32;
    __syncthreads();                     // prev tile's LDS reads done (all waves)
    if (i < cl) {
      #pragma unroll
      for (int c = 0; c < 4; ++c) {
        int gc = th + c * 128;
        {  // K: row 0..31, 16 chunks of 8; swizzle low 3 bits of chunk by row
          int row = gc >> 4, ci = gc & 15;
          int cs = (ci & 8) | ((ci ^ row) & 7);
          *(half8*)(KlH + row * 128 + cs * 8) = kpre[c];
        }
        {  // V: d-row 0..127, 4 chunks of 8; swizzle chunk by row (mod 4)
          int row = gc >> 2, ci = gc & 3;
          int cs = (ci ^ row) & 3;
          *(half8*)(VlH + row * 32 + cs * 8) = vpre[c];
        }
      }
    }
    __syncthreads();
    if (i + 1 < cl) {                    // issue next tile's global loads early
      int j1 = j0 + 32;
      #pragma unroll
      for (int c = 0; c < 4; ++c) {
        int gc = th + c * 128;
        kpre[c] = *(const half8*)(kbase + (long)(j1 + (gc >> 4)) * D_HEAD + (gc & 15) * 8);
        vpre[c] = *(const half8*)(vbase + (long)(gc >> 2) * S_LEN + j1 + (gc & 3) * 8);
      }
    }
    if (i >= cl) continue;               // idle tail iteration (hi half, odd n)

    // wave-uniform skip: tile outside this wave's 32-row window
    if (j0 + 31 < r0 - wl || j0 > r0 + 31 + wr) continue;

    float dscale = qs * kscb[tt >> 1] * sm_scale;   // kscale granularity = 64 keys

    // S^T = K Q^T : mfma(A=K-frag, B=Q-frag). Lane (qd,ln) gets, per nb,
    // S[qrow=ln][key = nb*16 + qd*4 + r] in sacc[mh][nb][r].
    floatx4 sacc[2][2];
    #pragma unroll
    for (int mh = 0; mh < 2; ++mh)
      #pragma unroll
      for (int nb = 0; nb < 2; ++nb) sacc[mh][nb] = (floatx4){0.f,0.f,0.f,0.f};
    #pragma unroll
    for (int nb = 0; nb < 2; ++nb)
      #pragma unroll
      for (int ks = 0; ks < 4; ++ks) {
        int ci = ks * 4 + qd;
        int cs = (ci & 8) | ((ci ^ ln) & 7);
        half8 kf = *(const half8*)(KlH + (nb * 16 + ln) * 128 + cs * 8);
        sacc[0][nb] = __builtin_amdgcn_mfma_f32_16x16x32_f16(kf, qa[0][ks], sacc[0][nb], 0, 0, 0);
        sacc[1][nb] = __builtin_amdgcn_mfma_f32_16x16x32_f16(kf, qa[1][ks], sacc[1][nb], 0, 0, 0);
      }

    // per-half: dequant + mask + online softmax (row = ln), defer-max,
    // in-register P pack into the single PV A-frag.
    half8 pa[2];
    #pragma unroll
    for (int mh = 0; mh < 2; ++mh) {
      int rb = r0 + mh * 16;
      bool need_mask = (j0 < rb + 15 - wl) || (j0 + 31 > rb + wr);
      int row = rb + ln;
      float sv[2][4];                    // [nb][r]
      #pragma unroll
      for (int nb = 0; nb < 2; ++nb)
        #pragma unroll
        for (int r = 0; r < 4; ++r) {
          float s = sacc[mh][nb][r] * dscale;
          if (need_mask) {
            int col = j0 + nb * 16 + qd * 4 + r;
            bool ok = (row - col <= wl) && (col - row <= wr);
            s = ok ? s : -1e30f;
          }
          sv[nb][r] = s;
        }
      float m0v = fmaxf(fmaxf(sv[0][0], sv[0][1]), fmaxf(sv[0][2], sv[0][3]));
      float m1v = fmaxf(fmaxf(sv[1][0], sv[1][1]), fmaxf(sv[1][2], sv[1][3]));
      float mx = fmaxf(m0v, m1v);
      mx = fmaxf(mx, __shfl_xor(mx, 16, 64));
      mx = fmaxf(mx, __shfl_xor(mx, 32, 64));

      if (__any(mx > mrow[mh] + 8.0f)) { // defer-max: rescale only on growth
        float mnew = fmaxf(mrow[mh], mx);
        float alpha = __expf(mrow[mh] - mnew);
        mrow[mh] = mnew;
        float ar[4];                     // alpha for C-layout rows qd*4+r
        #pragma unroll
        for (int r = 0; r < 4; ++r) ar[r] = __shfl(alpha, qd * 4 + r, 64);
        #pragma unroll
        for (int nd = 0; nd < 8; ++nd) {
          floatx4 o = oacc[mh][nd];
          #pragma unroll
          for (int r = 0; r < 4; ++r) o[r] *= ar[r];
          oacc[mh][nd] = o;
        }
        #pragma unroll
        for (int r = 0; r < 4; ++r) lacc[mh][r] *= ar[r];
      }

      float m0 = mrow[mh];
      // A-frag slot (lane qd, j): j=0..3 -> key qd*4+j ; j=4..7 -> key 16+qd*4+(j-4)
      half8 tf;
      #pragma unroll
      for (int r = 0; r < 4; ++r) {
        tf[r]     = (_Float16)__expf(sv[0][r] - m0);
        tf[4 + r] = (_Float16)__expf(sv[1][r] - m0);
      }
      pa[mh] = tf;
    }

    // O += P Vhat. V B-frag uses the SAME key permutation: slot (qd,j) ->
    // key 16*(j>>2) + qd*4 + (j&3): two b64 chunks at +0 and +16 keys.
    #pragma unroll
    for (int nd = 0; nd < 8; ++nd) {
      int rowv = nd * 16 + ln;
      int ci0 = qd >> 1;
      int o4 = (qd & 1) * 4;
      int cs0 = (ci0 ^ rowv) & 3;
      int cs1 = ((ci0 + 2) ^ rowv) & 3;
      half4 v0 = *(const half4*)(VlH + rowv * 32 + cs0 * 8 + o4);
      half4 v1 = *(const half4*)(VlH + rowv * 32 + cs1 * 8 + o4);
      half8 vf = { v0[0], v0[1], v0[2], v0[3], v1[0], v1[1], v1[2], v1[3] };
      oacc[0][nd] = __builtin_amdgcn_mfma_f32_16x16x32_f16(pa[0], vf, oacc[0][nd], 0, 0, 0);
      oacc[1][nd] = __builtin_amdgcn_mfma_f32_16x16x32_f16(pa[1], vf, oacc[1][nd], 0, 0, 0);
    }
    lacc[0] = __builtin_amdgcn_mfma_f32_16x16x32_f16(pa[0], vones, lacc[0], 0, 0, 0);
    lacc[1] = __builtin_amdgcn_mfma_f32_16x16x32_f16(pa[1], vones, lacc[1], 0, 0, 0);
  }

  // ---- combine the two key-halves (reuse smem as fp32 O buffer [2][32][128]) ----
  float* Ocmb = (float*)smem;
  __syncthreads();                       // all loop LDS reads done
  if (hf == 1 && qd == 0) {
    Mhi[wv2][ln] = mrow[0];
    Mhi[wv2][16 + ln] = mrow[1];
  }
  __syncthreads();
  float mmax[2];
  if (hf == 0) {
    #pragma unroll
    for (int mh = 0; mh < 2; ++mh)
      mmax[mh] = fmaxf(mrow[mh], Mhi[wv2][mh * 16 + ln]);
    if (qd == 0) {
      Mmax[wv2][ln] = mmax[0];
      Mmax[wv2][16 + ln] = mmax[1];
    }
  }
  __syncthreads();
  if (hf == 1) {
    #pragma unroll
    for (int mh = 0; mh < 2; ++mh) mmax[mh] = Mmax[wv2][mh * 16 + ln];
  }
  float ar[2][4];                        // alpha in C-layout rows qd*4+r
  #pragma unroll
  for (int mh = 0; mh < 2; ++mh) {
    float al = __expf(mrow[mh] - mmax[mh]);
    #pragma unroll
    for (int r = 0; r < 4; ++r) ar[mh][r] = __shfl(al, qd * 4 + r, 64);
  }
  if (hf == 1) {
    #pragma unroll
    for (int mh = 0; mh < 2; ++mh) {
      #pragma unroll
      for (int nd = 0; nd < 8; ++nd)
        #pragma unroll
        for (int r = 0; r < 4; ++r) {
          int rw = mh * 16 + qd * 4 + r;
          int col = nd * 16 + ln;
          int csw = (col + rw * 4) & 127;   // rotate-swizzle: stores 2-way-free
          Ocmb[(wv2 * 32 + rw) * 128 + csw] = oacc[mh][nd][r] * ar[mh][r];
        }
      if (ln == 0)
        #pragma unroll
        for (int r = 0; r < 4; ++r)
          Lhi[wv2][mh * 16 + qd * 4 + r] = lacc[mh][r] * ar[mh][r];
    }
  }
  __syncthreads();
  if (hf == 0) {
    float vm[8];
    #pragma unroll
    for (int nd = 0; nd < 8; ++nd)
      vm[nd] = vmean[bh * D_HEAD + nd * 16 + ln];
    float* obase = out + ((long)b * S_LEN) * NHID + h * D_HEAD;
    #pragma unroll
    for (int mh = 0; mh < 2; ++mh)
      #pragma unroll
      for (int r = 0; r < 4; ++r) {
        int rw = mh * 16 + qd * 4 + r;
        float lsum = lacc[mh][r] * ar[mh][r] + Lhi[wv2][rw];
        float linv = 1.0f / lsum;
        int row = r0 + rw;
        #pragma unroll
        for (int nd = 0; nd < 8; ++nd) {
          int col = nd * 16 + ln;
          int csw = (col + rw * 4) & 127;
          float o = oacc[mh][nd][r] * ar[mh][r] + Ocmb[(wv2 * 32 + rw) * 128 + csw];
          float o16 = (float)(_Float16)(o * linv);
          obase[(long)row * NHID + col] = o16 + vm[nd];
        }
      }
  }
}

extern "C" void kernel_launch(void* const* d_in, const int* in_sizes, int n_in,
                              void* d_out, int out_size, void* d_ws, size_t ws_size,
                              hipStream_t stream) {
  (void)in_sizes; (void)n_in; (void)out_size; (void)ws_size;
  const float* q = (const float*)d_in[0];
  const float* k = (const float*)d_in[1];
  const float* v = (const float*)d_in[2];
  const int* wl = (const int*)d_in[3];
  const int* wr = (const int*)d_in[4];
  float* out = (float*)d_out;

  char* ws = (char*)d_ws;
  size_t off = 0;
  const size_t tensz = (size_t)N_BH * S_LEN * D_HEAD * sizeof(_Float16);  // 16.78 MB
  _Float16* qq = (_Float16*)(ws + off); off += tensz;
  _Float16* kq = (_Float16*)(ws + off); off += tensz;
  _Float16* vt = (_Float16*)(ws + off); off += tensz;
  float* ksumP  = (float*)(ws + off); off += (size_t)N_BH * 16 * 128 * sizeof(float);
  float* vsumP  = (float*)(ws + off); off += (size_t)N_BH * 16 * 128 * sizeof(float);
  float* vmean  = (float*)(ws + off); off += N_BH * D_HEAD * sizeof(float);
  float* qscale = (float*)(ws + off); off += N_BH * 64 * sizeof(float);
  float* kscale = (float*)(ws + off); off += N_BH * 32 * sizeof(float);

  means_kernel<<<512, 256, 0, stream>>>(k, v, ksumP, vsumP);
  prep_kernel<<<4096, 256, 0, stream>>>(q, k, v, ksumP, vsumP, qq, kq, vt, qscale, kscale, vmean);
  attn_kernel<<<1024, 256, 0, stream>>>(qq, kq, vt, qscale, kscale, vmean, wl, wr, out);
}

// Round 5
// 513.385 us; speedup vs baseline: 1.6030x; 1.6030x over previous
//
#include <hip/hip_runtime.h>
#include <hip/hip_fp16.h>
#include <math.h>

#define S_LEN 2048
#define NHID  2048
#define D_HEAD 128
#define N_BH  32
#define EPS_Q 1e-8f

typedef _Float16 half8 __attribute__((ext_vector_type(8)));
typedef _Float16 half4 __attribute__((ext_vector_type(4)));
typedef float floatx4 __attribute__((ext_vector_type(4)));

// ---------------- kernel 1: per-(bh,chunk,d) partial sums of k and v ----------------
__global__ void means_kernel(const float* __restrict__ kk, const float* __restrict__ vv,
                             float* __restrict__ ksumP, float* __restrict__ vsumP) {
  int blk = blockIdx.x;            // 32 bh * 16 chunks of 128 rows
  int bh = blk >> 4, chunk = blk & 15;
  int b = bh >> 4, h = bh & 15;
  int t = threadIdx.x;
  int d4 = t & 31, sg = t >> 5;
  int s0 = chunk * 128;
  const long base = ((long)(b * S_LEN + s0)) * NHID + h * D_HEAD + d4 * 4;
  floatx4 ks = {0.f,0.f,0.f,0.f}, vs = {0.f,0.f,0.f,0.f};
  #pragma unroll 4
  for (int j = 0; j < 16; ++j) {
    long idx = base + (long)(sg * 16 + j) * NHID;
    ks += *(const floatx4*)(kk + idx);
    vs += *(const floatx4*)(vv + idx);
  }
  __shared__ floatx4 red[256];
  red[t] = ks; __syncthreads();
  if (t < 128) red[t] += red[t + 128]; __syncthreads();
  if (t < 64)  red[t] += red[t + 64];  __syncthreads();
  if (t < 32) *(floatx4*)(ksumP + (long)blk * 128 + t * 4) = red[t] + red[t + 32];
  __syncthreads();
  red[t] = vs; __syncthreads();
  if (t < 128) red[t] += red[t + 128]; __syncthreads();
  if (t < 64)  red[t] += red[t + 64];  __syncthreads();
  if (t < 32) *(floatx4*)(vsumP + (long)blk * 128 + t * 4) = red[t] + red[t + 32];
}

// ---------------- kernel 2 (fused): qquant | kquant | vprep ----------------
__global__ void prep_kernel(const float* __restrict__ q, const float* __restrict__ k,
                            const float* __restrict__ v,
                            const float* __restrict__ ksumP, const float* __restrict__ vsumP,
                            _Float16* __restrict__ qq, _Float16* __restrict__ kq,
                            _Float16* __restrict__ vt,
                            float* __restrict__ qscale, float* __restrict__ kscale,
                            float* __restrict__ vmean) {
  int blk = blockIdx.x;
  int t = threadIdx.x;
  int lane = t & 63, wid = t >> 6;
  __shared__ float wred[4];
  __shared__ __align__(16) _Float16 tile[64 * 136];
  int d4 = t & 31, sg = t >> 5;

  if (blk < 2048) {
    // ---- Q quant: 32 rows x 128 d
    int bh = blk >> 6, g = blk & 63;
    int b = bh >> 4, h = bh & 15;
    int s0 = g * 32;
    const long gbase = ((long)(b * S_LEN + s0)) * NHID + h * D_HEAD + d4 * 4;
    floatx4 vals[4]; float am = 0.f;
    #pragma unroll
    for (int j = 0; j < 4; ++j) {
      floatx4 x = *(const floatx4*)(q + gbase + (long)(sg + j * 8) * NHID);
      vals[j] = x;
      am = fmaxf(am, fmaxf(fmaxf(fabsf(x[0]), fabsf(x[1])), fmaxf(fabsf(x[2]), fabsf(x[3]))));
    }
    #pragma unroll
    for (int off = 1; off < 64; off <<= 1) am = fmaxf(am, __shfl_xor(am, off, 64));
    if (lane == 0) wred[wid] = am;
    __syncthreads();
    am = fmaxf(fmaxf(wred[0], wred[1]), fmaxf(wred[2], wred[3]));
    float scale = fmaxf(am / 127.0f, EPS_Q);
    if (t == 0) qscale[bh * 64 + g] = scale;
    float inv = 1.0f / scale;
    #pragma unroll
    for (int j = 0; j < 4; ++j) {
      half4 hv;
      #pragma unroll
      for (int c = 0; c < 4; ++c)
        hv[c] = (_Float16)fminf(fmaxf(rintf(vals[j][c] * inv), -127.f), 127.f);
      *(half4*)(qq + ((long)bh * S_LEN + s0 + sg + j * 8) * D_HEAD + d4 * 4) = hv;
    }
  } else if (blk < 3072) {
    // ---- K smooth+quant: 64 rows x 128 d
    int bb = blk - 2048;
    int bh = bb >> 5, g = bb & 31;
    int b = bh >> 4, h = bh & 15;
    int s0 = g * 64;
    floatx4 msum = {0.f,0.f,0.f,0.f};
    #pragma unroll
    for (int c = 0; c < 16; ++c)
      msum += *(const floatx4*)(ksumP + (long)(bh * 16 + c) * 128 + d4 * 4);
    floatx4 mean = msum * (1.0f / 2048.0f);
    const long gbase = ((long)(b * S_LEN + s0)) * NHID + h * D_HEAD + d4 * 4;
    floatx4 vals[8]; float am = 0.f;
    #pragma unroll
    for (int j = 0; j < 8; ++j) {
      floatx4 x = *(const floatx4*)(k + gbase + (long)(sg + j * 8) * NHID) - mean;
      vals[j] = x;
      am = fmaxf(am, fmaxf(fmaxf(fabsf(x[0]), fabsf(x[1])), fmaxf(fabsf(x[2]), fabsf(x[3]))));
    }
    #pragma unroll
    for (int off = 1; off < 64; off <<= 1) am = fmaxf(am, __shfl_xor(am, off, 64));
    if (lane == 0) wred[wid] = am;
    __syncthreads();
    am = fmaxf(fmaxf(wred[0], wred[1]), fmaxf(wred[2], wred[3]));
    float scale = fmaxf(am / 127.0f, EPS_Q);
    if (t == 0) kscale[bh * 32 + g] = scale;
    float inv = 1.0f / scale;
    #pragma unroll
    for (int j = 0; j < 8; ++j) {
      half4 hv;
      #pragma unroll
      for (int c = 0; c < 4; ++c)
        hv[c] = (_Float16)fminf(fmaxf(rintf(vals[j][c] * inv), -127.f), 127.f);
      *(half4*)(kq + ((long)bh * S_LEN + s0 + sg + j * 8) * D_HEAD + d4 * 4) = hv;
    }
  } else {
    // ---- V smooth -> fp16 transpose to [bh][d][s]
    int bb = blk - 3072;
    int bh = bb >> 5, st = bb & 31;
    int b = bh >> 4, h = bh & 15;
    int s0 = st * 64;
    floatx4 msum = {0.f,0.f,0.f,0.f};
    #pragma unroll
    for (int c = 0; c < 16; ++c)
      msum += *(const floatx4*)(vsumP + (long)(bh * 16 + c) * 128 + d4 * 4);
    floatx4 mean = msum * (1.0f / 2048.0f);
    if (st == 0 && sg == 0)
      *(floatx4*)(vmean + bh * D_HEAD + d4 * 4) = mean;
    const long gbase = ((long)(b * S_LEN + s0)) * NHID + h * D_HEAD + d4 * 4;
    #pragma unroll
    for (int j = 0; j < 8; ++j) {
      floatx4 x = *(const floatx4*)(v + gbase + (long)(sg + j * 8) * NHID) - mean;
      half4 hv = { (_Float16)x[0], (_Float16)x[1], (_Float16)x[2], (_Float16)x[3] };
      *(half4*)(tile + (sg + j * 8) * 136 + d4 * 4) = hv;
    }
    __syncthreads();
    int dr = t >> 1, sh = (t & 1) * 32;
    _Float16* dst = vt + ((long)bh * D_HEAD + dr) * S_LEN + s0 + sh;
    #pragma unroll
    for (int jo = 0; jo < 4; ++jo) {
      union { half8 v8; _Float16 h[8]; } u;
      #pragma unroll
      for (int ji = 0; ji < 8; ++ji) u.h[ji] = tile[(sh + jo * 8 + ji) * 136 + dr];
      *(half8*)(dst + jo * 8) = u.v8;
    }
  }
}

// ---------------- kernel 3: fused sliding-window attention ----------------
// v6 = v5 un-spilled + de-conflicted V:
//  * launch_bounds(256,3): R3/R4 showed any request for 4 waves/EU collapses
//    the arch-VGPR budget to 64 and spills (~1.6GB scratch, MfmaUtil 3%).
//    3 waves/EU (budget ~170; this kernel needs ~120) is the empirically
//    safe ceiling -> 3 blocks/CU x 4 waves = 12 waves/CU (1.5x v3).
//  * V LDS tile padded to stride 40 halfs (80B = 20 banks), NO swizzle:
//    v5's 4-chunk XOR swizzle put the b64 PV reads on 4 banks (22M conflict
//    cycles, 2x v3). Padding gives ~2-way (free per m136).
// Geometry: grid 1024 = 32 bh x 32 q-blocks of 64 rows; block = 4 waves =
// 2 q-strips x 2 key-halves; 32-key tiles; per-half K 8KB + V 10KB.
// Datapath per wave = v3 (swapped QK^T, in-register P, defer-max).
__launch_bounds__(256, 3)
__global__ void attn_kernel(const _Float16* __restrict__ qq, const _Float16* __restrict__ kq,
                            const _Float16* __restrict__ vt,
                            const float* __restrict__ qscale, const float* __restrict__ kscale,
                            const float* __restrict__ vmean,
                            const int* __restrict__ wlp, const int* __restrict__ wrp,
                            float* __restrict__ out) {
  int bid = blockIdx.x;
  int xcd = bid & 7, rest = bid >> 3;    // 4 bh per XCD: K/V working set 4MB = L2-resident
  int bh = xcd * 4 + (rest & 3);
  int qb = rest >> 2;                    // 0..31
  int b = bh >> 4, h = bh & 15;
  int q0 = qb * 64;

  int wl = *wlp; if (wl < 0) wl = S_LEN;
  int wr = *wrp; if (wr < 0) wr = S_LEN;

  int t = threadIdx.x;
  int wv = t >> 6;
  int hf = wv >> 1;                      // key-half: waves 0,1 = lo; 2,3 = hi
  int wv2 = wv & 1;                      // q-strip within block
  int th = t & 127;                      // thread id within the 2-wave half
  int lane = t & 63;
  int ln = lane & 15;
  int qd = lane >> 4;

  int r0 = q0 + wv2 * 32;                // this wave's 32 q rows

  // LDS: per-half K (32x128 swizzled, 8KB) + V (128 x stride-40 padded, 10KB);
  // same region reused as fp32 O-combine buffer [2][32][128] (32KB)
  __shared__ __align__(16) char smem[36864];
  __shared__ float Mhi[2][32];
  __shared__ float Mmax[2][32];
  __shared__ float Lhi[2][32];
  _Float16* KlH = (_Float16*)(smem + hf * 18432);          // [key 32][d 128] swizzled
  _Float16* VlH = (_Float16*)(smem + hf * 18432 + 8192);   // [d 128][key 32 pad 40]

  // Q fragments (MFMA B operand): lane (qd,ln) holds Q[r0+mh*16+ln][qd*8+j+32ks]
  half8 qa[2][4];
  #pragma unroll
  for (int mh = 0; mh < 2; ++mh) {
    const _Float16* qbase = qq + ((long)bh * S_LEN + r0 + mh * 16 + ln) * D_HEAD + qd * 8;
    #pragma unroll
    for (int ks = 0; ks < 4; ++ks)
      qa[mh][ks] = *(const half8*)(qbase + ks * 32);
  }
  float qs = qscale[bh * 64 + (r0 >> 5)];

  float mrow[2];                          // running max for q-row (ln) per half
  floatx4 lacc[2];                        // l in C-layout rows qd*4+r
  floatx4 oacc[2][8];
  #pragma unroll
  for (int mh = 0; mh < 2; ++mh) {
    mrow[mh] = -1e30f;
    #pragma unroll
    for (int r = 0; r < 4; ++r) lacc[mh][r] = 0.f;
    #pragma unroll
    for (int nd = 0; nd < 8; ++nd) oacc[mh][nd] = (floatx4){0.f,0.f,0.f,0.f};
  }

  int lo = q0 - wl; if (lo < 0) lo = 0;
  int hi = q0 + 63 + wr; if (hi > S_LEN - 1) hi = S_LEN - 1;
  int t_lo = lo >> 5, t_hi = hi >> 5;    // 32-key tiles
  int n = t_hi - t_lo + 1;
  int nh = (n + 1) >> 1;                 // lo half gets nh tiles, hi gets n-nh
  int sh0 = t_lo + hf * nh;              // this half's first tile
  int cl = hf ? (n - nh) : nh;           // this half's tile count (may be < nh)

  const float sm_scale = 0.08838834764831845f;  // 1/sqrt(128)
  const _Float16* kbase = kq + (long)bh * S_LEN * D_HEAD;
  const _Float16* vbase = vt + (long)bh * D_HEAD * S_LEN;
  const float* kscb = kscale + bh * 32;
  const half8 vones = { (_Float16)1, (_Float16)1, (_Float16)1, (_Float16)1,
                        (_Float16)1, (_Float16)1, (_Float16)1, (_Float16)1 };

  // register prefetch of this half's first tile (clamped if empty)
  half8 kpre[4], vpre[4];
  {
    int tp = sh0 > t_hi ? t_hi : sh0;
    int j0 = tp * 32;
    #pragma unroll
    for (int c = 0; c < 4; ++c) {
      int gc = th + c * 128;
      kpre[c] = *(const half8*)(kbase + (long)(j0 + (gc >> 4)) * D_HEAD + (gc & 15) * 8);
      vpre[c] = *(const half8*)(vbase + (long)(gc >> 2) * S_LEN + j0 + (gc & 3) * 8);
    }
  }

  for (int i = 0; i < nh; ++i) {
    int tt = sh0 + i;
    int j0 = tt * 32;
    __syncthreads();                     // prev tile's LDS reads done (all waves)
    if (i < cl) {
      #pragma unroll
      for (int c = 0; c < 4; ++c) {
        int gc = th + c * 128;
        {  // K: row 0..31, 16 chunks of 8; swizzle low 3 bits of chunk by row
          int row = gc >> 4, ci = gc & 15;
          int cs = (ci & 8) | ((ci ^ row) & 7);
          *(half8*)(KlH + row * 128 + cs * 8) = kpre[c];
        }
        {  // V: d-row 0..127, 4 chunks of 8; padded stride 40, no swizzle
          int row = gc >> 2, ci = gc & 3;
          *(half8*)(VlH + row * 40 + ci * 8) = vpre[c];
        }
      }
    }
    __syncthreads();
    if (i + 1 < cl) {                    // issue next tile's global loads early
      int j1 = j0 + 32;
      #pragma unroll
      for (int c = 0; c < 4; ++c) {
        int gc = th + c * 128;
        kpre[c] = *(const half8*)(kbase + (long)(j1 + (gc >> 4)) * D_HEAD + (gc & 15) * 8);
        vpre[c] = *(const half8*)(vbase + (long)(gc >> 2) * S_LEN + j1 + (gc & 3) * 8);
      }
    }
    if (i >= cl) continue;               // idle tail iteration (hi half, odd n)

    // wave-uniform skip: tile outside this wave's 32-row window
    if (j0 + 31 < r0 - wl || j0 > r0 + 31 + wr) continue;

    float dscale = qs * kscb[tt >> 1] * sm_scale;   // kscale granularity = 64 keys

    // S^T = K Q^T : mfma(A=K-frag, B=Q-frag). Lane (qd,ln) gets, per nb,
    // S[qrow=ln][key = nb*16 + qd*4 + r] in sacc[mh][nb][r].
    floatx4 sacc[2][2];
    #pragma unroll
    for (int mh = 0; mh < 2; ++mh)
      #pragma unroll
      for (int nb = 0; nb < 2; ++nb) sacc[mh][nb] = (floatx4){0.f,0.f,0.f,0.f};
    #pragma unroll
    for (int nb = 0; nb < 2; ++nb)
      #pragma unroll
      for (int ks = 0; ks < 4; ++ks) {
        int ci = ks * 4 + qd;
        int cs = (ci & 8) | ((ci ^ ln) & 7);
        half8 kf = *(const half8*)(KlH + (nb * 16 + ln) * 128 + cs * 8);
        sacc[0][nb] = __builtin_amdgcn_mfma_f32_16x16x32_f16(kf, qa[0][ks], sacc[0][nb], 0, 0, 0);
        sacc[1][nb] = __builtin_amdgcn_mfma_f32_16x16x32_f16(kf, qa[1][ks], sacc[1][nb], 0, 0, 0);
      }

    // per-half: dequant + mask + online softmax (row = ln), defer-max,
    // in-register P pack into the single PV A-frag.
    half8 pa[2];
    #pragma unroll
    for (int mh = 0; mh < 2; ++mh) {
      int rb = r0 + mh * 16;
      bool need_mask = (j0 < rb + 15 - wl) || (j0 + 31 > rb + wr);
      int row = rb + ln;
      float sv[2][4];                    // [nb][r]
      #pragma unroll
      for (int nb = 0; nb < 2; ++nb)
        #pragma unroll
        for (int r = 0; r < 4; ++r) {
          float s = sacc[mh][nb][r] * dscale;
          if (need_mask) {
            int col = j0 + nb * 16 + qd * 4 + r;
            bool ok = (row - col <= wl) && (col - row <= wr);
            s = ok ? s : -1e30f;
          }
          sv[nb][r] = s;
        }
      float m0v = fmaxf(fmaxf(sv[0][0], sv[0][1]), fmaxf(sv[0][2], sv[0][3]));
      float m1v = fmaxf(fmaxf(sv[1][0], sv[1][1]), fmaxf(sv[1][2], sv[1][3]));
      float mx = fmaxf(m0v, m1v);
      mx = fmaxf(mx, __shfl_xor(mx, 16, 64));
      mx = fmaxf(mx, __shfl_xor(mx, 32, 64));

      if (__any(mx > mrow[mh] + 8.0f)) { // defer-max: rescale only on growth
        float mnew = fmaxf(mrow[mh], mx);
        float alpha = __expf(mrow[mh] - mnew);
        mrow[mh] = mnew;
        float ar[4];                     // alpha for C-layout rows qd*4+r
        #pragma unroll
        for (int r = 0; r < 4; ++r) ar[r] = __shfl(alpha, qd * 4 + r, 64);
        #pragma unroll
        for (int nd = 0; nd < 8; ++nd) {
          floatx4 o = oacc[mh][nd];
          #pragma unroll
          for (int r = 0; r < 4; ++r) o[r] *= ar[r];
          oacc[mh][nd] = o;
        }
        #pragma unroll
        for (int r = 0; r < 4; ++r) lacc[mh][r] *= ar[r];
      }

      float m0 = mrow[mh];
      // A-frag slot (lane qd, j): j=0..3 -> key qd*4+j ; j=4..7 -> key 16+qd*4+(j-4)
      half8 tf;
      #pragma unroll
      for (int r = 0; r < 4; ++r) {
        tf[r]     = (_Float16)__expf(sv[0][r] - m0);
        tf[4 + r] = (_Float16)__expf(sv[1][r] - m0);
      }
      pa[mh] = tf;
    }

    // O += P Vhat. V B-frag uses the SAME key permutation: slot (qd,j) ->
    // key 16*(j>>2) + qd*4 + (j&3): two b64 chunks at +0 and +16 keys.
    #pragma unroll
    for (int nd = 0; nd < 8; ++nd) {
      int rowv = nd * 16 + ln;
      int ci0 = qd >> 1;
      int o4 = (qd & 1) * 4;
      half4 v0 = *(const half4*)(VlH + rowv * 40 + ci0 * 8 + o4);
      half4 v1 = *(const half4*)(VlH + rowv * 40 + (ci0 + 2) * 8 + o4);
      half8 vf = { v0[0], v0[1], v0[2], v0[3], v1[0], v1[1], v1[2], v1[3] };
      oacc[0][nd] = __builtin_amdgcn_mfma_f32_16x16x32_f16(pa[0], vf, oacc[0][nd], 0, 0, 0);
      oacc[1][nd] = __builtin_amdgcn_mfma_f32_16x16x32_f16(pa[1], vf, oacc[1][nd], 0, 0, 0);
    }
    lacc[0] = __builtin_amdgcn_mfma_f32_16x16x32_f16(pa[0], vones, lacc[0], 0, 0, 0);
    lacc[1] = __builtin_amdgcn_mfma_f32_16x16x32_f16(pa[1], vones, lacc[1], 0, 0, 0);
  }

  // ---- combine the two key-halves (reuse smem as fp32 O buffer [2][32][128]) ----
  float* Ocmb = (float*)smem;
  __syncthreads();                       // all loop LDS reads done
  if (hf == 1 && qd == 0) {
    Mhi[wv2][ln] = mrow[0];
    Mhi[wv2][16 + ln] = mrow[1];
  }
  __syncthreads();
  float mmax[2];
  if (hf == 0) {
    #pragma unroll
    for (int mh = 0; mh < 2; ++mh)
      mmax[mh] = fmaxf(mrow[mh], Mhi[wv2][mh * 16 + ln]);
    if (qd == 0) {
      Mmax[wv2][ln] = mmax[0];
      Mmax[wv2][16 + ln] = mmax[1];
    }
  }
  __syncthreads();
  if (hf == 1) {
    #pragma unroll
    for (int mh = 0; mh < 2; ++mh) mmax[mh] = Mmax[wv2][mh * 16 + ln];
  }
  float ar[2][4];                        // alpha in C-layout rows qd*4+r
  #pragma unroll
  for (int mh = 0; mh < 2; ++mh) {
    float al = __expf(mrow[mh] - mmax[mh]);
    #pragma unroll
    for (int r = 0; r < 4; ++r) ar[mh][r] = __shfl(al, qd * 4 + r, 64);
  }
  if (hf == 1) {
    #pragma unroll
    for (int mh = 0; mh < 2; ++mh) {
      #pragma unroll
      for (int nd = 0; nd < 8; ++nd)
        #pragma unroll
        for (int r = 0; r < 4; ++r) {
          int rw = mh * 16 + qd * 4 + r;
          int col = nd * 16 + ln;
          int csw = (col + rw * 4) & 127;   // rotate-swizzle: stores 2-way-free
          Ocmb[(wv2 * 32 + rw) * 128 + csw] = oacc[mh][nd][r] * ar[mh][r];
        }
      if (ln == 0)
        #pragma unroll
        for (int r = 0; r < 4; ++r)
          Lhi[wv2][mh * 16 + qd * 4 + r] = lacc[mh][r] * ar[mh][r];
    }
  }
  __syncthreads();
  if (hf == 0) {
    float vm[8];
    #pragma unroll
    for (int nd = 0; nd < 8; ++nd)
      vm[nd] = vmean[bh * D_HEAD + nd * 16 + ln];
    float* obase = out + ((long)b * S_LEN) * NHID + h * D_HEAD;
    #pragma unroll
    for (int mh = 0; mh < 2; ++mh)
      #pragma unroll
      for (int r = 0; r < 4; ++r) {
        int rw = mh * 16 + qd * 4 + r;
        float lsum = lacc[mh][r] * ar[mh][r] + Lhi[wv2][rw];
        float linv = 1.0f / lsum;
        int row = r0 + rw;
        #pragma unroll
        for (int nd = 0; nd < 8; ++nd) {
          int col = nd * 16 + ln;
          int csw = (col + rw * 4) & 127;
          float o = oacc[mh][nd][r] * ar[mh][r] + Ocmb[(wv2 * 32 + rw) * 128 + csw];
          float o16 = (float)(_Float16)(o * linv);
          obase[(long)row * NHID + col] = o16 + vm[nd];
        }
      }
  }
}

extern "C" void kernel_launch(void* const* d_in, const int* in_sizes, int n_in,
                              void* d_out, int out_size, void* d_ws, size_t ws_size,
                              hipStream_t stream) {
  (void)in_sizes; (void)n_in; (void)out_size; (void)ws_size;
  const float* q = (const float*)d_in[0];
  const float* k = (const float*)d_in[1];
  const float* v = (const float*)d_in[2];
  const int* wl = (const int*)d_in[3];
  const int* wr = (const int*)d_in[4];
  float* out = (float*)d_out;

  char* ws = (char*)d_ws;
  size_t off = 0;
  const size_t tensz = (size_t)N_BH * S_LEN * D_HEAD * sizeof(_Float16);  // 16.78 MB
  _Float16* qq = (_Float16*)(ws + off); off += tensz;
  _Float16* kq = (_Float16*)(ws + off); off += tensz;
  _Float16* vt = (_Float16*)(ws + off); off += tensz;
  float* ksumP  = (float*)(ws + off); off += (size_t)N_BH * 16 * 128 * sizeof(float);
  float* vsumP  = (float*)(ws + off); off += (size_t)N_BH * 16 * 128 * sizeof(float);
  float* vmean  = (float*)(ws + off); off += N_BH * D_HEAD * sizeof(float);
  float* qscale = (float*)(ws + off); off += N_BH * 64 * sizeof(float);
  float* kscale = (float*)(ws + off); off += N_BH * 32 * sizeof(float);

  means_kernel<<<512, 256, 0, stream>>>(k, v, ksumP, vsumP);
  prep_kernel<<<4096, 256, 0, stream>>>(q, k, v, ksumP, vsumP, qq, kq, vt, qscale, kscale, vmean);
  attn_kernel<<<1024, 256, 0, stream>>>(qq, kq, vt, qscale, kscale, vmean, wl, wr, out);
}

// Round 6
// 249.175 us; speedup vs baseline: 3.3028x; 2.0603x over previous
//
#include <hip/hip_runtime.h>
#include <hip/hip_fp16.h>
#include <math.h>

#define S_LEN 2048
#define NHID  2048
#define D_HEAD 128
#define N_BH  32
#define EPS_Q 1e-8f

typedef _Float16 half8 __attribute__((ext_vector_type(8)));
typedef _Float16 half4 __attribute__((ext_vector_type(4)));
typedef float floatx4 __attribute__((ext_vector_type(4)));

// ---------------- kernel 1: per-(bh,chunk,d) partial sums of k and v ----------------
__global__ void means_kernel(const float* __restrict__ kk, const float* __restrict__ vv,
                             float* __restrict__ ksumP, float* __restrict__ vsumP) {
  int blk = blockIdx.x;            // 32 bh * 16 chunks of 128 rows
  int bh = blk >> 4, chunk = blk & 15;
  int b = bh >> 4, h = bh & 15;
  int t = threadIdx.x;
  int d4 = t & 31, sg = t >> 5;
  int s0 = chunk * 128;
  const long base = ((long)(b * S_LEN + s0)) * NHID + h * D_HEAD + d4 * 4;
  floatx4 ks = {0.f,0.f,0.f,0.f}, vs = {0.f,0.f,0.f,0.f};
  #pragma unroll 4
  for (int j = 0; j < 16; ++j) {
    long idx = base + (long)(sg * 16 + j) * NHID;
    ks += *(const floatx4*)(kk + idx);
    vs += *(const floatx4*)(vv + idx);
  }
  __shared__ floatx4 red[256];
  red[t] = ks; __syncthreads();
  if (t < 128) red[t] += red[t + 128]; __syncthreads();
  if (t < 64)  red[t] += red[t + 64];  __syncthreads();
  if (t < 32) *(floatx4*)(ksumP + (long)blk * 128 + t * 4) = red[t] + red[t + 32];
  __syncthreads();
  red[t] = vs; __syncthreads();
  if (t < 128) red[t] += red[t + 128]; __syncthreads();
  if (t < 64)  red[t] += red[t + 64];  __syncthreads();
  if (t < 32) *(floatx4*)(vsumP + (long)blk * 128 + t * 4) = red[t] + red[t + 32];
}

// ---------------- kernel 2 (fused): qquant | kquant | vprep ----------------
__global__ void prep_kernel(const float* __restrict__ q, const float* __restrict__ k,
                            const float* __restrict__ v,
                            const float* __restrict__ ksumP, const float* __restrict__ vsumP,
                            _Float16* __restrict__ qq, _Float16* __restrict__ kq,
                            _Float16* __restrict__ vt,
                            float* __restrict__ qscale, float* __restrict__ kscale,
                            float* __restrict__ vmean) {
  int blk = blockIdx.x;
  int t = threadIdx.x;
  int lane = t & 63, wid = t >> 6;
  __shared__ float wred[4];
  __shared__ __align__(16) _Float16 tile[64 * 136];
  int d4 = t & 31, sg = t >> 5;

  if (blk < 2048) {
    // ---- Q quant: 32 rows x 128 d
    int bh = blk >> 6, g = blk & 63;
    int b = bh >> 4, h = bh & 15;
    int s0 = g * 32;
    const long gbase = ((long)(b * S_LEN + s0)) * NHID + h * D_HEAD + d4 * 4;
    floatx4 vals[4]; float am = 0.f;
    #pragma unroll
    for (int j = 0; j < 4; ++j) {
      floatx4 x = *(const floatx4*)(q + gbase + (long)(sg + j * 8) * NHID);
      vals[j] = x;
      am = fmaxf(am, fmaxf(fmaxf(fabsf(x[0]), fabsf(x[1])), fmaxf(fabsf(x[2]), fabsf(x[3]))));
    }
    #pragma unroll
    for (int off = 1; off < 64; off <<= 1) am = fmaxf(am, __shfl_xor(am, off, 64));
    if (lane == 0) wred[wid] = am;
    __syncthreads();
    am = fmaxf(fmaxf(wred[0], wred[1]), fmaxf(wred[2], wred[3]));
    float scale = fmaxf(am / 127.0f, EPS_Q);
    if (t == 0) qscale[bh * 64 + g] = scale;
    float inv = 1.0f / scale;
    #pragma unroll
    for (int j = 0; j < 4; ++j) {
      half4 hv;
      #pragma unroll
      for (int c = 0; c < 4; ++c)
        hv[c] = (_Float16)fminf(fmaxf(rintf(vals[j][c] * inv), -127.f), 127.f);
      *(half4*)(qq + ((long)bh * S_LEN + s0 + sg + j * 8) * D_HEAD + d4 * 4) = hv;
    }
  } else if (blk < 3072) {
    // ---- K smooth+quant: 64 rows x 128 d
    int bb = blk - 2048;
    int bh = bb >> 5, g = bb & 31;
    int b = bh >> 4, h = bh & 15;
    int s0 = g * 64;
    floatx4 msum = {0.f,0.f,0.f,0.f};
    #pragma unroll
    for (int c = 0; c < 16; ++c)
      msum += *(const floatx4*)(ksumP + (long)(bh * 16 + c) * 128 + d4 * 4);
    floatx4 mean = msum * (1.0f / 2048.0f);
    const long gbase = ((long)(b * S_LEN + s0)) * NHID + h * D_HEAD + d4 * 4;
    floatx4 vals[8]; float am = 0.f;
    #pragma unroll
    for (int j = 0; j < 8; ++j) {
      floatx4 x = *(const floatx4*)(k + gbase + (long)(sg + j * 8) * NHID) - mean;
      vals[j] = x;
      am = fmaxf(am, fmaxf(fmaxf(fabsf(x[0]), fabsf(x[1])), fmaxf(fabsf(x[2]), fabsf(x[3]))));
    }
    #pragma unroll
    for (int off = 1; off < 64; off <<= 1) am = fmaxf(am, __shfl_xor(am, off, 64));
    if (lane == 0) wred[wid] = am;
    __syncthreads();
    am = fmaxf(fmaxf(wred[0], wred[1]), fmaxf(wred[2], wred[3]));
    float scale = fmaxf(am / 127.0f, EPS_Q);
    if (t == 0) kscale[bh * 32 + g] = scale;
    float inv = 1.0f / scale;
    #pragma unroll
    for (int j = 0; j < 8; ++j) {
      half4 hv;
      #pragma unroll
      for (int c = 0; c < 4; ++c)
        hv[c] = (_Float16)fminf(fmaxf(rintf(vals[j][c] * inv), -127.f), 127.f);
      *(half4*)(kq + ((long)bh * S_LEN + s0 + sg + j * 8) * D_HEAD + d4 * 4) = hv;
    }
  } else {
    // ---- V smooth -> fp16 transpose to [bh][d][s]
    int bb = blk - 3072;
    int bh = bb >> 5, st = bb & 31;
    int b = bh >> 4, h = bh & 15;
    int s0 = st * 64;
    floatx4 msum = {0.f,0.f,0.f,0.f};
    #pragma unroll
    for (int c = 0; c < 16; ++c)
      msum += *(const floatx4*)(vsumP + (long)(bh * 16 + c) * 128 + d4 * 4);
    floatx4 mean = msum * (1.0f / 2048.0f);
    if (st == 0 && sg == 0)
      *(floatx4*)(vmean + bh * D_HEAD + d4 * 4) = mean;
    const long gbase = ((long)(b * S_LEN + s0)) * NHID + h * D_HEAD + d4 * 4;
    #pragma unroll
    for (int j = 0; j < 8; ++j) {
      floatx4 x = *(const floatx4*)(v + gbase + (long)(sg + j * 8) * NHID) - mean;
      half4 hv = { (_Float16)x[0], (_Float16)x[1], (_Float16)x[2], (_Float16)x[3] };
      *(half4*)(tile + (sg + j * 8) * 136 + d4 * 4) = hv;
    }
    __syncthreads();
    int dr = t >> 1, sh = (t & 1) * 32;
    _Float16* dst = vt + ((long)bh * D_HEAD + dr) * S_LEN + s0 + sh;
    #pragma unroll
    for (int jo = 0; jo < 4; ++jo) {
      union { half8 v8; _Float16 h[8]; } u;
      #pragma unroll
      for (int ji = 0; ji < 8; ++ji) u.h[ji] = tile[(sh + jo * 8 + ji) * 136 + dr];
      *(half8*)(dst + jo * 8) = u.v8;
    }
  }
}

// ---------------- kernel 3: fused sliding-window attention ----------------
// v7 = v3 (proven 105us; the (256,3)/(256,4) occupancy arc of R3-R5 all
// spilled — this datapath fits only (256,2), 8 waves/CU) + ILP pipeline:
//  * K/V double-buffered (2x32KB = 64KB, still 2 blocks/CU): per tile,
//    {ds_write t+1 -> buf[nxt]} || {global load t+2 -> regs} || {compute t
//    from buf[cur]} then ONE barrier (v3 had 2 barriers + serialized stage).
//    Writes to buf[nxt] are safe pre-barrier: its last reads were at t-1,
//    separated by the end-of-(t-1) barrier.
//  * s_setprio(1) around QK and PV MFMA clusters (T5: +4-7% attn).
//  * softmax in exp2 domain (log2e folded into dscale; v_exp IS exp2).
__launch_bounds__(256, 2)
__global__ void attn_kernel(const _Float16* __restrict__ qq, const _Float16* __restrict__ kq,
                            const _Float16* __restrict__ vt,
                            const float* __restrict__ qscale, const float* __restrict__ kscale,
                            const float* __restrict__ vmean,
                            const int* __restrict__ wlp, const int* __restrict__ wrp,
                            float* __restrict__ out) {
  int bid = blockIdx.x;
  int xcd = bid & 7, rest = bid >> 3;
  int bh = xcd * 4 + (rest & 3);
  int qb = rest >> 2;
  int b = bh >> 4, h = bh & 15;
  int q0 = qb * 128;

  int wl = *wlp; if (wl < 0) wl = S_LEN;
  int wr = *wrp; if (wr < 0) wr = S_LEN;

  int t = threadIdx.x;
  int wv = t >> 6;
  int lane = t & 63;
  int ln = lane & 15;
  int qd = lane >> 4;

  int r0 = q0 + wv * 32;                   // this wave's 32 q rows

  __shared__ __align__(16) _Float16 Kl[2][64 * 128];   // [buf][key][d], chunk-XOR swz
  __shared__ __align__(16) _Float16 Vl[2][128 * 64];   // [buf][d][key], chunk-XOR swz

  // Q fragments (MFMA B operand): lane (qd,ln) holds Q[r0+mh*16+ln][qd*8+j+32ks]
  half8 qa[2][4];
  #pragma unroll
  for (int mh = 0; mh < 2; ++mh) {
    const _Float16* qbase = qq + ((long)bh * S_LEN + r0 + mh * 16 + ln) * D_HEAD + qd * 8;
    #pragma unroll
    for (int ks = 0; ks < 4; ++ks)
      qa[mh][ks] = *(const half8*)(qbase + ks * 32);
  }
  float qs = qscale[bh * 64 + (r0 >> 5)];

  float mrow[2];                            // running max (log2 domain), q-row = ln
  floatx4 lacc[2];                          // l in C-layout rows qd*4+r
  floatx4 oacc[2][8];
  #pragma unroll
  for (int mh = 0; mh < 2; ++mh) {
    mrow[mh] = -1e30f;
    #pragma unroll
    for (int r = 0; r < 4; ++r) lacc[mh][r] = 0.f;
    #pragma unroll
    for (int nd = 0; nd < 8; ++nd) oacc[mh][nd] = (floatx4){0.f,0.f,0.f,0.f};
  }

  int lo = q0 - wl; if (lo < 0) lo = 0;
  int hi = q0 + 127 + wr; if (hi > S_LEN - 1) hi = S_LEN - 1;
  int t_lo = lo >> 6, t_hi = hi >> 6;

  const float sm_scale2 = 0.08838834764831845f * 1.4426950408889634f;  // /sqrt(128)*log2e
  const _Float16* kbase = kq + (long)bh * S_LEN * D_HEAD;
  const _Float16* vbase = vt + (long)bh * D_HEAD * S_LEN;
  const float* kscb = kscale + bh * 32;
  const half8 vones = { (_Float16)1, (_Float16)1, (_Float16)1, (_Float16)1,
                        (_Float16)1, (_Float16)1, (_Float16)1, (_Float16)1 };

  half8 kpre[4], vpre[4];

#define LOAD_PRE(TILE)                                                              \
  {                                                                                 \
    int j0_ = (TILE) * 64;                                                          \
    _Pragma("unroll")                                                               \
    for (int c = 0; c < 4; ++c) {                                                   \
      int gc = t + c * 256;                                                         \
      kpre[c] = *(const half8*)(kbase + (long)(j0_ + (gc >> 4)) * D_HEAD + (gc & 15) * 8); \
      vpre[c] = *(const half8*)(vbase + (long)(gc >> 3) * S_LEN + j0_ + (gc & 7) * 8);     \
    }                                                                               \
  }

#define STAGE_TO(BB)                                                                \
  {                                                                                 \
    _Float16* Kb = &Kl[BB][0];                                                      \
    _Float16* Vb = &Vl[BB][0];                                                      \
    _Pragma("unroll")                                                               \
    for (int c = 0; c < 4; ++c) {                                                   \
      int gc = t + c * 256;                                                         \
      { int row = gc >> 4, ci = gc & 15;                                            \
        int cs = (ci & 8) | ((ci ^ row) & 7);                                       \
        *(half8*)(Kb + row * 128 + cs * 8) = kpre[c]; }                             \
      { int row = gc >> 3, ci = gc & 7;                                             \
        int cs = (ci ^ row) & 7;                                                    \
        *(half8*)(Vb + row * 64 + cs * 8) = vpre[c]; }                              \
    }                                                                               \
  }

  // prologue: tile t_lo -> buf0; then preload t_lo+1 into regs
  LOAD_PRE(t_lo);
  STAGE_TO(0);
  __syncthreads();
  if (t_lo + 1 <= t_hi) LOAD_PRE(t_lo + 1);

  for (int tt = t_lo; tt <= t_hi; ++tt) {
    int j0 = tt * 64;
    int cur = (tt - t_lo) & 1;

    // stage tile tt+1 into the other buffer (its last readers finished at
    // tile tt-1, separated by that iteration's barrier), then refill regs
    // with tile tt+2 — both overlap this tile's compute below.
    if (tt + 1 <= t_hi) {
      STAGE_TO(cur ^ 1);
      if (tt + 2 <= t_hi) LOAD_PRE(tt + 2);
    }

    // wave-uniform skip: tile outside this wave's 32-row window
    if (!(j0 + 63 < r0 - wl || j0 > r0 + 31 + wr)) {
      const _Float16* Kc = &Kl[cur][0];
      const _Float16* Vc = &Vl[cur][0];
      float dscale2 = qs * kscb[tt] * sm_scale2;

      // S^T = K Q^T : mfma(A=K-frag, B=Q-frag). Lane (qd,ln) gets, per nb,
      // S[qrow=ln][key = nb*16 + qd*4 + r] in sacc[mh][nb][r].
      floatx4 sacc[2][4];
      #pragma unroll
      for (int mh = 0; mh < 2; ++mh)
        #pragma unroll
        for (int nb = 0; nb < 4; ++nb) sacc[mh][nb] = (floatx4){0.f,0.f,0.f,0.f};
      __builtin_amdgcn_s_setprio(1);
      #pragma unroll
      for (int nb = 0; nb < 4; ++nb)
        #pragma unroll
        for (int ks = 0; ks < 4; ++ks) {
          int ci = ks * 4 + qd;
          int cs = (ci & 8) | ((ci ^ ln) & 7);
          half8 kf = *(const half8*)(Kc + (nb * 16 + ln) * 128 + cs * 8);
          sacc[0][nb] = __builtin_amdgcn_mfma_f32_16x16x32_f16(kf, qa[0][ks], sacc[0][nb], 0, 0, 0);
          sacc[1][nb] = __builtin_amdgcn_mfma_f32_16x16x32_f16(kf, qa[1][ks], sacc[1][nb], 0, 0, 0);
        }
      __builtin_amdgcn_s_setprio(0);

      // per-half: dequant (log2 domain) + mask + online softmax (row = ln),
      // defer-max, in-register P pack into PV A-frags.
      half8 pa[2][2];
      #pragma unroll
      for (int mh = 0; mh < 2; ++mh) {
        int rb = r0 + mh * 16;
        bool need_mask = (j0 < rb + 15 - wl) || (j0 + 63 > rb + wr);
        int row = rb + ln;
        float sv[4][4];                    // [nb][r]
        float mnb[4];
        #pragma unroll
        for (int nb = 0; nb < 4; ++nb) {
          #pragma unroll
          for (int r = 0; r < 4; ++r) {
            float s = sacc[mh][nb][r] * dscale2;
            if (need_mask) {
              int col = j0 + nb * 16 + qd * 4 + r;
              bool ok = (row - col <= wl) && (col - row <= wr);
              s = ok ? s : -1e30f;
            }
            sv[nb][r] = s;
          }
          mnb[nb] = fmaxf(fmaxf(sv[nb][0], sv[nb][1]), fmaxf(sv[nb][2], sv[nb][3]));
        }
        float mx = fmaxf(fmaxf(mnb[0], mnb[1]), fmaxf(mnb[2], mnb[3]));
        mx = fmaxf(mx, __shfl_xor(mx, 16, 64));
        mx = fmaxf(mx, __shfl_xor(mx, 32, 64));

        if (__any(mx > mrow[mh] + 8.0f)) { // defer-max: rescale only on growth
          float mnew = fmaxf(mrow[mh], mx);
          float alpha = __builtin_amdgcn_exp2f(mrow[mh] - mnew);
          mrow[mh] = mnew;
          float ar[4];                     // alpha for C-layout rows qd*4+r
          #pragma unroll
          for (int r = 0; r < 4; ++r) ar[r] = __shfl(alpha, qd * 4 + r, 64);
          #pragma unroll
          for (int nd = 0; nd < 8; ++nd) {
            floatx4 o = oacc[mh][nd];
            #pragma unroll
            for (int r = 0; r < 4; ++r) o[r] *= ar[r];
            oacc[mh][nd] = o;
          }
          #pragma unroll
          for (int r = 0; r < 4; ++r) lacc[mh][r] *= ar[r];
        }

        float m0 = mrow[mh];
        // A-frag slot (ks,qd,j): j=0..3 -> key 32ks+qd*4+j ; j=4..7 -> +16
        #pragma unroll
        for (int ks = 0; ks < 2; ++ks) {
          half8 tf;
          #pragma unroll
          for (int r = 0; r < 4; ++r) {
            tf[r]     = (_Float16)__builtin_amdgcn_exp2f(sv[2 * ks][r] - m0);
            tf[4 + r] = (_Float16)__builtin_amdgcn_exp2f(sv[2 * ks + 1][r] - m0);
          }
          pa[mh][ks] = tf;
        }
      }

      // O += P Vhat. V B-frag uses the SAME key permutation: slot (ks,qd,j) ->
      // key 32ks + 16*(j>>2) + qd*4 + (j&3): two b64 chunks at +0 / +16 keys.
      __builtin_amdgcn_s_setprio(1);
      #pragma unroll
      for (int nd = 0; nd < 8; ++nd) {
        int rowv = nd * 16 + ln;
        #pragma unroll
        for (int ks = 0; ks < 2; ++ks) {
          int ci0 = ks * 4 + (qd >> 1);
          int o4 = (qd & 1) * 4;
          int cs0 = (ci0 ^ rowv) & 7;
          int cs1 = ((ci0 + 2) ^ rowv) & 7;
          half4 v0 = *(const half4*)(Vc + rowv * 64 + cs0 * 8 + o4);
          half4 v1 = *(const half4*)(Vc + rowv * 64 + cs1 * 8 + o4);
          half8 vf = { v0[0], v0[1], v0[2], v0[3], v1[0], v1[1], v1[2], v1[3] };
          oacc[0][nd] = __builtin_amdgcn_mfma_f32_16x16x32_f16(pa[0][ks], vf, oacc[0][nd], 0, 0, 0);
          oacc[1][nd] = __builtin_amdgcn_mfma_f32_16x16x32_f16(pa[1][ks], vf, oacc[1][nd], 0, 0, 0);
        }
      }
      #pragma unroll
      for (int mh = 0; mh < 2; ++mh) {
        lacc[mh] = __builtin_amdgcn_mfma_f32_16x16x32_f16(pa[mh][0], vones, lacc[mh], 0, 0, 0);
        lacc[mh] = __builtin_amdgcn_mfma_f32_16x16x32_f16(pa[mh][1], vones, lacc[mh], 0, 0, 0);
      }
      __builtin_amdgcn_s_setprio(0);
    }

    __syncthreads();                       // single barrier per tile
  }

  // epilogue: out = fp16(O/l) + v_mean  (oacc/lacc rows = qd*4+r, cols = ln)
  float vm[8];
  #pragma unroll
  for (int nd = 0; nd < 8; ++nd)
    vm[nd] = vmean[bh * D_HEAD + nd * 16 + ln];
  float* obase = out + ((long)b * S_LEN) * NHID + h * D_HEAD;
  #pragma unroll
  for (int mh = 0; mh < 2; ++mh)
    #pragma unroll
    for (int r = 0; r < 4; ++r) {
      int row = r0 + mh * 16 + qd * 4 + r;
      float linv = 1.0f / lacc[mh][r];
      #pragma unroll
      for (int nd = 0; nd < 8; ++nd) {
        float o16 = (float)(_Float16)(oacc[mh][nd][r] * linv);
        obase[(long)row * NHID + nd * 16 + ln] = o16 + vm[nd];
      }
    }
#undef LOAD_PRE
#undef STAGE_TO
}

extern "C" void kernel_launch(void* const* d_in, const int* in_sizes, int n_in,
                              void* d_out, int out_size, void* d_ws, size_t ws_size,
                              hipStream_t stream) {
  (void)in_sizes; (void)n_in; (void)out_size; (void)ws_size;
  const float* q = (const float*)d_in[0];
  const float* k = (const float*)d_in[1];
  const float* v = (const float*)d_in[2];
  const int* wl = (const int*)d_in[3];
  const int* wr = (const int*)d_in[4];
  float* out = (float*)d_out;

  char* ws = (char*)d_ws;
  size_t off = 0;
  const size_t tensz = (size_t)N_BH * S_LEN * D_HEAD * sizeof(_Float16);  // 16.78 MB
  _Float16* qq = (_Float16*)(ws + off); off += tensz;
  _Float16* kq = (_Float16*)(ws + off); off += tensz;
  _Float16* vt = (_Float16*)(ws + off); off += tensz;
  float* ksumP  = (float*)(ws + off); off += (size_t)N_BH * 16 * 128 * sizeof(float);
  float* vsumP  = (float*)(ws + off); off += (size_t)N_BH * 16 * 128 * sizeof(float);
  float* vmean  = (float*)(ws + off); off += N_BH * D_HEAD * sizeof(float);
  float* qscale = (float*)(ws + off); off += N_BH * 64 * sizeof(float);
  float* kscale = (float*)(ws + off); off += N_BH * 32 * sizeof(float);

  means_kernel<<<512, 256, 0, stream>>>(k, v, ksumP, vsumP);
  prep_kernel<<<4096, 256, 0, stream>>>(q, k, v, ksumP, vsumP, qq, kq, vt, qscale, kscale, vmean);
  attn_kernel<<<512, 256, 0, stream>>>(qq, kq, vt, qscale, kscale, vmean, wl, wr, out);
}

// Round 7
// 236.962 us; speedup vs baseline: 3.4731x; 1.0515x over previous
//
#include <hip/hip_runtime.h>
#include <hip/hip_fp16.h>
#include <math.h>

#define S_LEN 2048
#define NHID  2048
#define D_HEAD 128
#define N_BH  32
#define EPS_Q 1e-8f

typedef _Float16 half8 __attribute__((ext_vector_type(8)));
typedef _Float16 half4 __attribute__((ext_vector_type(4)));
typedef float floatx4 __attribute__((ext_vector_type(4)));
typedef int int4v __attribute__((ext_vector_type(4)));
typedef signed char int8_t_;

// ---------------- kernel 1: per-(bh,chunk,d) partial sums of k and v ----------------
__global__ void means_kernel(const float* __restrict__ kk, const float* __restrict__ vv,
                             float* __restrict__ ksumP, float* __restrict__ vsumP) {
  int blk = blockIdx.x;            // 32 bh * 16 chunks of 128 rows
  int bh = blk >> 4, chunk = blk & 15;
  int b = bh >> 4, h = bh & 15;
  int t = threadIdx.x;
  int d4 = t & 31, sg = t >> 5;
  int s0 = chunk * 128;
  const long base = ((long)(b * S_LEN + s0)) * NHID + h * D_HEAD + d4 * 4;
  floatx4 ks = {0.f,0.f,0.f,0.f}, vs = {0.f,0.f,0.f,0.f};
  #pragma unroll 4
  for (int j = 0; j < 16; ++j) {
    long idx = base + (long)(sg * 16 + j) * NHID;
    ks += *(const floatx4*)(kk + idx);
    vs += *(const floatx4*)(vv + idx);
  }
  __shared__ floatx4 red[256];
  red[t] = ks; __syncthreads();
  if (t < 128) red[t] += red[t + 128]; __syncthreads();
  if (t < 64)  red[t] += red[t + 64];  __syncthreads();
  if (t < 32) *(floatx4*)(ksumP + (long)blk * 128 + t * 4) = red[t] + red[t + 32];
  __syncthreads();
  red[t] = vs; __syncthreads();
  if (t < 128) red[t] += red[t + 128]; __syncthreads();
  if (t < 64)  red[t] += red[t + 64];  __syncthreads();
  if (t < 32) *(floatx4*)(vsumP + (long)blk * 128 + t * 4) = red[t] + red[t + 32];
}

// ---------------- kernel 2 (fused): qquant | kquant | vprep ----------------
// qq/kq now emitted as packed int8 (4 vals per int store) — halves write traffic
// and feeds attn's i8 QK path.
__global__ void prep_kernel(const float* __restrict__ q, const float* __restrict__ k,
                            const float* __restrict__ v,
                            const float* __restrict__ ksumP, const float* __restrict__ vsumP,
                            signed char* __restrict__ qq, signed char* __restrict__ kq,
                            _Float16* __restrict__ vt,
                            float* __restrict__ qscale, float* __restrict__ kscale,
                            float* __restrict__ vmean) {
  int blk = blockIdx.x;
  int t = threadIdx.x;
  int lane = t & 63, wid = t >> 6;
  __shared__ float wred[4];
  __shared__ __align__(16) _Float16 tile[64 * 136];
  int d4 = t & 31, sg = t >> 5;

  if (blk < 2048) {
    // ---- Q quant: 32 rows x 128 d
    int bh = blk >> 6, g = blk & 63;
    int b = bh >> 4, h = bh & 15;
    int s0 = g * 32;
    const long gbase = ((long)(b * S_LEN + s0)) * NHID + h * D_HEAD + d4 * 4;
    floatx4 vals[4]; float am = 0.f;
    #pragma unroll
    for (int j = 0; j < 4; ++j) {
      floatx4 x = *(const floatx4*)(q + gbase + (long)(sg + j * 8) * NHID);
      vals[j] = x;
      am = fmaxf(am, fmaxf(fmaxf(fabsf(x[0]), fabsf(x[1])), fmaxf(fabsf(x[2]), fabsf(x[3]))));
    }
    #pragma unroll
    for (int off = 1; off < 64; off <<= 1) am = fmaxf(am, __shfl_xor(am, off, 64));
    if (lane == 0) wred[wid] = am;
    __syncthreads();
    am = fmaxf(fmaxf(wred[0], wred[1]), fmaxf(wred[2], wred[3]));
    float scale = fmaxf(am / 127.0f, EPS_Q);
    if (t == 0) qscale[bh * 64 + g] = scale;
    float inv = 1.0f / scale;
    #pragma unroll
    for (int j = 0; j < 4; ++j) {
      int pk = 0;
      #pragma unroll
      for (int c = 0; c < 4; ++c) {
        int qv = (int)fminf(fmaxf(rintf(vals[j][c] * inv), -127.f), 127.f);
        pk |= (qv & 255) << (8 * c);
      }
      ((int*)qq)[((long)bh * S_LEN + s0 + sg + j * 8) * 32 + d4] = pk;
    }
  } else if (blk < 3072) {
    // ---- K smooth+quant: 64 rows x 128 d
    int bb = blk - 2048;
    int bh = bb >> 5, g = bb & 31;
    int b = bh >> 4, h = bh & 15;
    int s0 = g * 64;
    floatx4 msum = {0.f,0.f,0.f,0.f};
    #pragma unroll
    for (int c = 0; c < 16; ++c)
      msum += *(const floatx4*)(ksumP + (long)(bh * 16 + c) * 128 + d4 * 4);
    floatx4 mean = msum * (1.0f / 2048.0f);
    const long gbase = ((long)(b * S_LEN + s0)) * NHID + h * D_HEAD + d4 * 4;
    floatx4 vals[8]; float am = 0.f;
    #pragma unroll
    for (int j = 0; j < 8; ++j) {
      floatx4 x = *(const floatx4*)(k + gbase + (long)(sg + j * 8) * NHID) - mean;
      vals[j] = x;
      am = fmaxf(am, fmaxf(fmaxf(fabsf(x[0]), fabsf(x[1])), fmaxf(fabsf(x[2]), fabsf(x[3]))));
    }
    #pragma unroll
    for (int off = 1; off < 64; off <<= 1) am = fmaxf(am, __shfl_xor(am, off, 64));
    if (lane == 0) wred[wid] = am;
    __syncthreads();
    am = fmaxf(fmaxf(wred[0], wred[1]), fmaxf(wred[2], wred[3]));
    float scale = fmaxf(am / 127.0f, EPS_Q);
    if (t == 0) kscale[bh * 32 + g] = scale;
    float inv = 1.0f / scale;
    #pragma unroll
    for (int j = 0; j < 8; ++j) {
      int pk = 0;
      #pragma unroll
      for (int c = 0; c < 4; ++c) {
        int qv = (int)fminf(fmaxf(rintf(vals[j][c] * inv), -127.f), 127.f);
        pk |= (qv & 255) << (8 * c);
      }
      ((int*)kq)[((long)bh * S_LEN + s0 + sg + j * 8) * 32 + d4] = pk;
    }
  } else {
    // ---- V smooth -> fp16 transpose to [bh][d][s]
    int bb = blk - 3072;
    int bh = bb >> 5, st = bb & 31;
    int b = bh >> 4, h = bh & 15;
    int s0 = st * 64;
    floatx4 msum = {0.f,0.f,0.f,0.f};
    #pragma unroll
    for (int c = 0; c < 16; ++c)
      msum += *(const floatx4*)(vsumP + (long)(bh * 16 + c) * 128 + d4 * 4);
    floatx4 mean = msum * (1.0f / 2048.0f);
    if (st == 0 && sg == 0)
      *(floatx4*)(vmean + bh * D_HEAD + d4 * 4) = mean;
    const long gbase = ((long)(b * S_LEN + s0)) * NHID + h * D_HEAD + d4 * 4;
    #pragma unroll
    for (int j = 0; j < 8; ++j) {
      floatx4 x = *(const floatx4*)(v + gbase + (long)(sg + j * 8) * NHID) - mean;
      half4 hv = { (_Float16)x[0], (_Float16)x[1], (_Float16)x[2], (_Float16)x[3] };
      *(half4*)(tile + (sg + j * 8) * 136 + d4 * 4) = hv;
    }
    __syncthreads();
    int dr = t >> 1, sh = (t & 1) * 32;
    _Float16* dst = vt + ((long)bh * D_HEAD + dr) * S_LEN + s0 + sh;
    #pragma unroll
    for (int jo = 0; jo < 4; ++jo) {
      union { half8 v8; _Float16 h[8]; } u;
      #pragma unroll
      for (int ji = 0; ji < 8; ++ji) u.h[ji] = tile[(sh + jo * 8 + ji) * 136 + dr];
      *(half8*)(dst + jo * 8) = u.v8;
    }
  }
}

// ---------------- kernel 3: fused sliding-window attention ----------------
// v8 = v3 (proven 105us: 2-barrier schedule, (256,2), swapped QK^T, in-reg P,
// defer-max) with the QK path moved to int8 MFMA (mfma_i32_16x16x64_i8):
//  * 2x K-depth per instruction at 2x OPS rate -> QK MFMAs 32 -> 16 per
//    tile/wave; K LDS reads 16 -> 8 b128; K tile 16KB -> 8KB; kq/qq half size.
//  * i8 4-reg operand layout: m/n = lane&15, k = (lane>>4)*16 + byte (direct
//    scaling of the verified f16 k=(lane>>4)*8+j mapping); C layout is
//    shape-determined (dtype-independent) so everything downstream of sacc
//    is v3 verbatim. int32 accumulation exact; dequant = cvt+mul.
// V path / softmax / PV (f16) / epilogue / schedule: v3 unchanged.
__launch_bounds__(256, 2)
__global__ void attn_kernel(const signed char* __restrict__ qq, const signed char* __restrict__ kq,
                            const _Float16* __restrict__ vt,
                            const float* __restrict__ qscale, const float* __restrict__ kscale,
                            const float* __restrict__ vmean,
                            const int* __restrict__ wlp, const int* __restrict__ wrp,
                            float* __restrict__ out) {
  int bid = blockIdx.x;
  int xcd = bid & 7, rest = bid >> 3;
  int bh = xcd * 4 + (rest & 3);
  int qb = rest >> 2;
  int b = bh >> 4, h = bh & 15;
  int q0 = qb * 128;

  int wl = *wlp; if (wl < 0) wl = S_LEN;
  int wr = *wrp; if (wr < 0) wr = S_LEN;

  int t = threadIdx.x;
  int wv = t >> 6;
  int lane = t & 63;
  int ln = lane & 15;
  int qd = lane >> 4;

  int r0 = q0 + wv * 32;                   // this wave's 32 q rows

  __shared__ __align__(16) signed char Kl[64 * 128];  // [key][k-byte], 8x16B chunks XOR swz
  __shared__ __align__(16) _Float16 Vl[128 * 64];     // [d][key], chunk-XOR swizzled

  // Q fragments (MFMA B operand, i8): lane (qd,ln) holds Q[r0+mh*16+ln][k=64ks2+qd*16..+15]
  int4v qa8[2][2];
  #pragma unroll
  for (int mh = 0; mh < 2; ++mh) {
    const signed char* qbase = qq + ((long)bh * S_LEN + r0 + mh * 16 + ln) * 128 + qd * 16;
    #pragma unroll
    for (int ks2 = 0; ks2 < 2; ++ks2)
      qa8[mh][ks2] = *(const int4v*)(qbase + ks2 * 64);
  }
  float qs = qscale[bh * 64 + (r0 >> 5)];

  float mrow[2];                            // running max for q-row (ln) per half
  floatx4 lacc[2];                          // l in C-layout rows qd*4+r (matches oacc)
  floatx4 oacc[2][8];
  #pragma unroll
  for (int mh = 0; mh < 2; ++mh) {
    mrow[mh] = -1e30f;
    #pragma unroll
    for (int r = 0; r < 4; ++r) lacc[mh][r] = 0.f;
    #pragma unroll
    for (int nd = 0; nd < 8; ++nd) oacc[mh][nd] = (floatx4){0.f,0.f,0.f,0.f};
  }

  int lo = q0 - wl; if (lo < 0) lo = 0;
  int hi = q0 + 127 + wr; if (hi > S_LEN - 1) hi = S_LEN - 1;
  int t_lo = lo >> 6, t_hi = hi >> 6;

  const float sm_scale = 0.08838834764831845f;  // 1/sqrt(128)
  const signed char* kbase = kq + (long)bh * S_LEN * 128;
  const _Float16* vbase = vt + (long)bh * D_HEAD * S_LEN;
  const float* kscb = kscale + bh * 32;
  const half8 vones = { (_Float16)1, (_Float16)1, (_Float16)1, (_Float16)1,
                        (_Float16)1, (_Float16)1, (_Float16)1, (_Float16)1 };

  // register prefetch of first tile (same gc decomposition as the stores below)
  int4v kpre[2];
  half8 vpre[4];
  {
    int j0 = t_lo * 64;
    #pragma unroll
    for (int c = 0; c < 2; ++c) {
      int gc = t + c * 256;                // 512 chunks: 64 rows x 8 chunks of 16B
      kpre[c] = *(const int4v*)(kbase + (long)(j0 + (gc >> 3)) * 128 + (gc & 7) * 16);
    }
    #pragma unroll
    for (int c = 0; c < 4; ++c) {
      int gc = t + c * 256;                // 1024 chunks: 128 d-rows x 8 chunks of 8 halfs
      vpre[c] = *(const half8*)(vbase + (long)(gc >> 3) * S_LEN + j0 + (gc & 7) * 8);
    }
  }

  for (int tt = t_lo; tt <= t_hi; ++tt) {
    int j0 = tt * 64;
    __syncthreads();                       // prev tile's LDS reads done
    #pragma unroll
    for (int c = 0; c < 2; ++c) {          // K: row 0..63, 8 chunks of 16B; XOR by row
      int gc = t + c * 256;
      int row = gc >> 3, ci = gc & 7;
      int cs = (ci ^ row) & 7;
      *(int4v*)(Kl + row * 128 + cs * 16) = kpre[c];
    }
    #pragma unroll
    for (int c = 0; c < 4; ++c) {          // V: d-row 0..127, 8 chunks of 8 halfs
      int gc = t + c * 256;
      int row = gc >> 3, ci = gc & 7;
      int cs = (ci ^ row) & 7;
      *(half8*)(Vl + row * 64 + cs * 8) = vpre[c];
    }
    __syncthreads();
    if (tt < t_hi) {                       // issue next tile's global loads early
      int j1 = j0 + 64;
      #pragma unroll
      for (int c = 0; c < 2; ++c) {
        int gc = t + c * 256;
        kpre[c] = *(const int4v*)(kbase + (long)(j1 + (gc >> 3)) * 128 + (gc & 7) * 16);
      }
      #pragma unroll
      for (int c = 0; c < 4; ++c) {
        int gc = t + c * 256;
        vpre[c] = *(const half8*)(vbase + (long)(gc >> 3) * S_LEN + j1 + (gc & 7) * 8);
      }
    }

    // wave-uniform skip: tile outside this wave's 32-row window
    if (j0 + 63 < r0 - wl || j0 > r0 + 31 + wr) continue;

    float dscale = qs * kscb[tt] * sm_scale;

    // S^T = K Q^T in int8: mfma_i32(A=K-frag, B=Q-frag). Lane (qd,ln) gets,
    // per nb, S[qrow=ln][key = nb*16 + qd*4 + r] in isacc[mh][nb][r] (int32).
    int4v isacc[2][4];
    #pragma unroll
    for (int mh = 0; mh < 2; ++mh)
      #pragma unroll
      for (int nb = 0; nb < 4; ++nb) isacc[mh][nb] = (int4v){0,0,0,0};
    #pragma unroll
    for (int nb = 0; nb < 4; ++nb)
      #pragma unroll
      for (int ks2 = 0; ks2 < 2; ++ks2) {
        int ci = ks2 * 4 + qd;             // logical 16B chunk = k-bytes ci*16..+15
        int cs = (ci ^ ln) & 7;
        int4v kf = *(const int4v*)(Kl + (nb * 16 + ln) * 128 + cs * 16);
        isacc[0][nb] = __builtin_amdgcn_mfma_i32_16x16x64_i8(kf, qa8[0][ks2], isacc[0][nb], 0, 0, 0);
        isacc[1][nb] = __builtin_amdgcn_mfma_i32_16x16x64_i8(kf, qa8[1][ks2], isacc[1][nb], 0, 0, 0);
      }

    // per-half: dequant + mask + online softmax (row = ln, in-lane + 2
    // shuffles), defer-max rescale, in-register P pack into PV A-frags.
    half8 pa[2][2];
    #pragma unroll
    for (int mh = 0; mh < 2; ++mh) {
      int rb = r0 + mh * 16;
      bool need_mask = (j0 < rb + 15 - wl) || (j0 + 63 > rb + wr);
      int row = rb + ln;
      float sv[4][4];                      // [nb][r]
      float mnb[4];
      #pragma unroll
      for (int nb = 0; nb < 4; ++nb) {
        #pragma unroll
        for (int r = 0; r < 4; ++r) {
          float s = (float)isacc[mh][nb][r] * dscale;
          if (need_mask) {
            int col = j0 + nb * 16 + qd * 4 + r;
            bool ok = (row - col <= wl) && (col - row <= wr);
            s = ok ? s : -1e30f;
          }
          sv[nb][r] = s;
        }
        mnb[nb] = fmaxf(fmaxf(sv[nb][0], sv[nb][1]), fmaxf(sv[nb][2], sv[nb][3]));
      }
      float mx = fmaxf(fmaxf(mnb[0], mnb[1]), fmaxf(mnb[2], mnb[3]));
      mx = fmaxf(mx, __shfl_xor(mx, 16, 64));
      mx = fmaxf(mx, __shfl_xor(mx, 32, 64));

      if (__any(mx > mrow[mh] + 8.0f)) {   // defer-max: rescale only on growth
        float mnew = fmaxf(mrow[mh], mx);
        float alpha = __expf(mrow[mh] - mnew);
        mrow[mh] = mnew;
        float ar[4];                       // alpha for C-layout rows qd*4+r
        #pragma unroll
        for (int r = 0; r < 4; ++r) ar[r] = __shfl(alpha, qd * 4 + r, 64);
        #pragma unroll
        for (int nd = 0; nd < 8; ++nd) {
          floatx4 o = oacc[mh][nd];
          #pragma unroll
          for (int r = 0; r < 4; ++r) o[r] *= ar[r];
          oacc[mh][nd] = o;
        }
        #pragma unroll
        for (int r = 0; r < 4; ++r) lacc[mh][r] *= ar[r];
      }

      float m0 = mrow[mh];
      // A-frag slot (ks, lane qd, j): j=0..3 -> key 32ks+qd*4+j ; j=4..7 -> +16
      #pragma unroll
      for (int ks = 0; ks < 2; ++ks) {
        half8 tf;
        #pragma unroll
        for (int r = 0; r < 4; ++r) {
          tf[r]     = (_Float16)__expf(sv[2 * ks][r] - m0);
          tf[4 + r] = (_Float16)__expf(sv[2 * ks + 1][r] - m0);
        }
        pa[mh][ks] = tf;
      }
    }

    // O += P Vhat. V B-frag uses the SAME key permutation: slot (ks,qd,j) ->
    // key 32ks + 16*(j>>2) + qd*4 + (j&3): two b64 chunks at +0 and +16 keys.
    #pragma unroll
    for (int nd = 0; nd < 8; ++nd) {
      int rowv = nd * 16 + ln;
      #pragma unroll
      for (int ks = 0; ks < 2; ++ks) {
        int ci0 = ks * 4 + (qd >> 1);
        int o4 = (qd & 1) * 4;
        int cs0 = (ci0 ^ rowv) & 7;
        int cs1 = ((ci0 + 2) ^ rowv) & 7;
        half4 v0 = *(const half4*)(Vl + rowv * 64 + cs0 * 8 + o4);
        half4 v1 = *(const half4*)(Vl + rowv * 64 + cs1 * 8 + o4);
        half8 vf = { v0[0], v0[1], v0[2], v0[3], v1[0], v1[1], v1[2], v1[3] };
        oacc[0][nd] = __builtin_amdgcn_mfma_f32_16x16x32_f16(pa[0][ks], vf, oacc[0][nd], 0, 0, 0);
        oacc[1][nd] = __builtin_amdgcn_mfma_f32_16x16x32_f16(pa[1][ks], vf, oacc[1][nd], 0, 0, 0);
      }
    }
    #pragma unroll
    for (int mh = 0; mh < 2; ++mh) {
      lacc[mh] = __builtin_amdgcn_mfma_f32_16x16x32_f16(pa[mh][0], vones, lacc[mh], 0, 0, 0);
      lacc[mh] = __builtin_amdgcn_mfma_f32_16x16x32_f16(pa[mh][1], vones, lacc[mh], 0, 0, 0);
    }
  }

  // epilogue: out = fp16(O/l) + v_mean  (oacc/lacc rows = qd*4+r, cols = ln)
  float vm[8];
  #pragma unroll
  for (int nd = 0; nd < 8; ++nd)
    vm[nd] = vmean[bh * D_HEAD + nd * 16 + ln];
  float* obase = out + ((long)b * S_LEN) * NHID + h * D_HEAD;
  #pragma unroll
  for (int mh = 0; mh < 2; ++mh)
    #pragma unroll
    for (int r = 0; r < 4; ++r) {
      int row = r0 + mh * 16 + qd * 4 + r;
      float linv = 1.0f / lacc[mh][r];
      #pragma unroll
      for (int nd = 0; nd < 8; ++nd) {
        float o16 = (float)(_Float16)(oacc[mh][nd][r] * linv);
        obase[(long)row * NHID + nd * 16 + ln] = o16 + vm[nd];
      }
    }
}

extern "C" void kernel_launch(void* const* d_in, const int* in_sizes, int n_in,
                              void* d_out, int out_size, void* d_ws, size_t ws_size,
                              hipStream_t stream) {
  (void)in_sizes; (void)n_in; (void)out_size; (void)ws_size;
  const float* q = (const float*)d_in[0];
  const float* k = (const float*)d_in[1];
  const float* v = (const float*)d_in[2];
  const int* wl = (const int*)d_in[3];
  const int* wr = (const int*)d_in[4];
  float* out = (float*)d_out;

  char* ws = (char*)d_ws;
  size_t off = 0;
  const size_t i8sz = (size_t)N_BH * S_LEN * D_HEAD;                      // 8.39 MB
  const size_t f16sz = (size_t)N_BH * S_LEN * D_HEAD * sizeof(_Float16); // 16.78 MB
  signed char* qq = (signed char*)(ws + off); off += i8sz;
  signed char* kq = (signed char*)(ws + off); off += i8sz;
  _Float16* vt = (_Float16*)(ws + off); off += f16sz;
  float* ksumP  = (float*)(ws + off); off += (size_t)N_BH * 16 * 128 * sizeof(float);
  float* vsumP  = (float*)(ws + off); off += (size_t)N_BH * 16 * 128 * sizeof(float);
  float* vmean  = (float*)(ws + off); off += N_BH * D_HEAD * sizeof(float);
  float* qscale = (float*)(ws + off); off += N_BH * 64 * sizeof(float);
  float* kscale = (float*)(ws + off); off += N_BH * 32 * sizeof(float);

  means_kernel<<<512, 256, 0, stream>>>(k, v, ksumP, vsumP);
  prep_kernel<<<4096, 256, 0, stream>>>(q, k, v, ksumP, vsumP, qq, kq, vt, qscale, kscale, vmean);
  attn_kernel<<<512, 256, 0, stream>>>(qq, kq, vt, qscale, kscale, vmean, wl, wr, out);
}

// Round 8
// 223.142 us; speedup vs baseline: 3.6881x; 1.0619x over previous
//
#include <hip/hip_runtime.h>
#include <hip/hip_fp16.h>
#include <math.h>

#define S_LEN 2048
#define NHID  2048
#define D_HEAD 128
#define N_BH  32
#define EPS_Q 1e-8f

typedef _Float16 half8 __attribute__((ext_vector_type(8)));
typedef _Float16 half4 __attribute__((ext_vector_type(4)));
typedef float floatx4 __attribute__((ext_vector_type(4)));
typedef int int4v __attribute__((ext_vector_type(4)));

// ---------------- kernel 1: per-(bh,chunk,d) partial sums of k and v ----------------
// v2: 1024 blocks (64-row chunks, 4 blocks/CU) for better BW spread than 512.
__global__ void means_kernel(const float* __restrict__ kk, const float* __restrict__ vv,
                             float* __restrict__ ksumP, float* __restrict__ vsumP) {
  int blk = blockIdx.x;            // 32 bh * 32 chunks of 64 rows
  int bh = blk >> 5, chunk = blk & 31;
  int b = bh >> 4, h = bh & 15;
  int t = threadIdx.x;
  int d4 = t & 31, sg = t >> 5;
  int s0 = chunk * 64;
  const long base = ((long)(b * S_LEN + s0)) * NHID + h * D_HEAD + d4 * 4;
  floatx4 ks = {0.f,0.f,0.f,0.f}, vs = {0.f,0.f,0.f,0.f};
  #pragma unroll
  for (int j = 0; j < 8; ++j) {
    long idx = base + (long)(sg * 8 + j) * NHID;
    ks += *(const floatx4*)(kk + idx);
    vs += *(const floatx4*)(vv + idx);
  }
  __shared__ floatx4 red[256];
  red[t] = ks; __syncthreads();
  if (t < 128) red[t] += red[t + 128]; __syncthreads();
  if (t < 64)  red[t] += red[t + 64];  __syncthreads();
  if (t < 32) *(floatx4*)(ksumP + (long)blk * 128 + t * 4) = red[t] + red[t + 32];
  __syncthreads();
  red[t] = vs; __syncthreads();
  if (t < 128) red[t] += red[t + 128]; __syncthreads();
  if (t < 64)  red[t] += red[t + 64];  __syncthreads();
  if (t < 32) *(floatx4*)(vsumP + (long)blk * 128 + t * 4) = red[t] + red[t + 32];
}

// ---------------- kernel 2 (fused): qquant | kquant | vprep ----------------
__global__ void prep_kernel(const float* __restrict__ q, const float* __restrict__ k,
                            const float* __restrict__ v,
                            const float* __restrict__ ksumP, const float* __restrict__ vsumP,
                            signed char* __restrict__ qq, signed char* __restrict__ kq,
                            _Float16* __restrict__ vt,
                            float* __restrict__ qscale, float* __restrict__ kscale,
                            float* __restrict__ vmean) {
  int blk = blockIdx.x;
  int t = threadIdx.x;
  int lane = t & 63, wid = t >> 6;
  __shared__ float wred[4];
  __shared__ __align__(16) _Float16 tile[64 * 136];
  int d4 = t & 31, sg = t >> 5;

  if (blk < 2048) {
    // ---- Q quant: 32 rows x 128 d
    int bh = blk >> 6, g = blk & 63;
    int b = bh >> 4, h = bh & 15;
    int s0 = g * 32;
    const long gbase = ((long)(b * S_LEN + s0)) * NHID + h * D_HEAD + d4 * 4;
    floatx4 vals[4]; float am = 0.f;
    #pragma unroll
    for (int j = 0; j < 4; ++j) {
      floatx4 x = *(const floatx4*)(q + gbase + (long)(sg + j * 8) * NHID);
      vals[j] = x;
      am = fmaxf(am, fmaxf(fmaxf(fabsf(x[0]), fabsf(x[1])), fmaxf(fabsf(x[2]), fabsf(x[3]))));
    }
    #pragma unroll
    for (int off = 1; off < 64; off <<= 1) am = fmaxf(am, __shfl_xor(am, off, 64));
    if (lane == 0) wred[wid] = am;
    __syncthreads();
    am = fmaxf(fmaxf(wred[0], wred[1]), fmaxf(wred[2], wred[3]));
    float scale = fmaxf(am / 127.0f, EPS_Q);
    if (t == 0) qscale[bh * 64 + g] = scale;
    float inv = 1.0f / scale;
    #pragma unroll
    for (int j = 0; j < 4; ++j) {
      int pk = 0;
      #pragma unroll
      for (int c = 0; c < 4; ++c) {
        int qv = (int)fminf(fmaxf(rintf(vals[j][c] * inv), -127.f), 127.f);
        pk |= (qv & 255) << (8 * c);
      }
      ((int*)qq)[((long)bh * S_LEN + s0 + sg + j * 8) * 32 + d4] = pk;
    }
  } else if (blk < 3072) {
    // ---- K smooth+quant: 64 rows x 128 d
    int bb = blk - 2048;
    int bh = bb >> 5, g = bb & 31;
    int b = bh >> 4, h = bh & 15;
    int s0 = g * 64;
    floatx4 msum = {0.f,0.f,0.f,0.f};
    #pragma unroll
    for (int c = 0; c < 32; ++c)
      msum += *(const floatx4*)(ksumP + (long)(bh * 32 + c) * 128 + d4 * 4);
    floatx4 mean = msum * (1.0f / 2048.0f);
    const long gbase = ((long)(b * S_LEN + s0)) * NHID + h * D_HEAD + d4 * 4;
    floatx4 vals[8]; float am = 0.f;
    #pragma unroll
    for (int j = 0; j < 8; ++j) {
      floatx4 x = *(const floatx4*)(k + gbase + (long)(sg + j * 8) * NHID) - mean;
      vals[j] = x;
      am = fmaxf(am, fmaxf(fmaxf(fabsf(x[0]), fabsf(x[1])), fmaxf(fabsf(x[2]), fabsf(x[3]))));
    }
    #pragma unroll
    for (int off = 1; off < 64; off <<= 1) am = fmaxf(am, __shfl_xor(am, off, 64));
    if (lane == 0) wred[wid] = am;
    __syncthreads();
    am = fmaxf(fmaxf(wred[0], wred[1]), fmaxf(wred[2], wred[3]));
    float scale = fmaxf(am / 127.0f, EPS_Q);
    if (t == 0) kscale[bh * 32 + g] = scale;
    float inv = 1.0f / scale;
    #pragma unroll
    for (int j = 0; j < 8; ++j) {
      int pk = 0;
      #pragma unroll
      for (int c = 0; c < 4; ++c) {
        int qv = (int)fminf(fmaxf(rintf(vals[j][c] * inv), -127.f), 127.f);
        pk |= (qv & 255) << (8 * c);
      }
      ((int*)kq)[((long)bh * S_LEN + s0 + sg + j * 8) * 32 + d4] = pk;
    }
  } else {
    // ---- V smooth -> fp16 transpose to [bh][d][s]
    int bb = blk - 3072;
    int bh = bb >> 5, st = bb & 31;
    int b = bh >> 4, h = bh & 15;
    int s0 = st * 64;
    floatx4 msum = {0.f,0.f,0.f,0.f};
    #pragma unroll
    for (int c = 0; c < 32; ++c)
      msum += *(const floatx4*)(vsumP + (long)(bh * 32 + c) * 128 + d4 * 4);
    floatx4 mean = msum * (1.0f / 2048.0f);
    if (st == 0 && sg == 0)
      *(floatx4*)(vmean + bh * D_HEAD + d4 * 4) = mean;
    const long gbase = ((long)(b * S_LEN + s0)) * NHID + h * D_HEAD + d4 * 4;
    #pragma unroll
    for (int j = 0; j < 8; ++j) {
      floatx4 x = *(const floatx4*)(v + gbase + (long)(sg + j * 8) * NHID) - mean;
      half4 hv = { (_Float16)x[0], (_Float16)x[1], (_Float16)x[2], (_Float16)x[3] };
      *(half4*)(tile + (sg + j * 8) * 136 + d4 * 4) = hv;
    }
    __syncthreads();
    int dr = t >> 1, sh = (t & 1) * 32;
    _Float16* dst = vt + ((long)bh * D_HEAD + dr) * S_LEN + s0 + sh;
    #pragma unroll
    for (int jo = 0; jo < 4; ++jo) {
      union { half8 v8; _Float16 h[8]; } u;
      #pragma unroll
      for (int ji = 0; ji < 8; ++ji) u.h[ji] = tile[(sh + jo * 8 + ji) * 136 + dr];
      *(half8*)(dst + jo * 8) = u.v8;
    }
  }
}

// ---------------- kernel 3: fused sliding-window attention ----------------
// v9 = v8 (i8 QK, 102.5us) + VALU-lean softmax:
//  * row-max computed on RAW int32 scores (argmax-invariant, dscale>0):
//    v_max_i32 tree + 2 int shuffles; one cvt+mul per row to get f32 max.
//  * exp2-domain: log2e folded into dscale2; per score p =
//    exp2(fma(cvt(s_int), dscale2, -m0)) — fma replaces mul+sub, exp2
//    replaces __expf's mul+exp. Saves ~64 VALU/(mh,tile,wave) of the
//    ~47%-busy VALU stream (R7's dominant pipe).
//  * defer threshold 11.5 = 8*log2e (same true-domain semantics).
// Masked scores -> int -2^30 (hazard parity with the old -1e30 path).
// Schedule/PV/epilogue: v8 unchanged. (256,2): R3-R5 proved any higher
// waves/EU request splits the unified RF and spills this datapath.
__launch_bounds__(256, 2)
__global__ void attn_kernel(const signed char* __restrict__ qq, const signed char* __restrict__ kq,
                            const _Float16* __restrict__ vt,
                            const float* __restrict__ qscale, const float* __restrict__ kscale,
                            const float* __restrict__ vmean,
                            const int* __restrict__ wlp, const int* __restrict__ wrp,
                            float* __restrict__ out) {
  int bid = blockIdx.x;
  int xcd = bid & 7, rest = bid >> 3;
  int bh = xcd * 4 + (rest & 3);
  int qb = rest >> 2;
  int b = bh >> 4, h = bh & 15;
  int q0 = qb * 128;

  int wl = *wlp; if (wl < 0) wl = S_LEN;
  int wr = *wrp; if (wr < 0) wr = S_LEN;

  int t = threadIdx.x;
  int wv = t >> 6;
  int lane = t & 63;
  int ln = lane & 15;
  int qd = lane >> 4;

  int r0 = q0 + wv * 32;                   // this wave's 32 q rows

  __shared__ __align__(16) signed char Kl[64 * 128];  // [key][k-byte], 8x16B chunks XOR swz
  __shared__ __align__(16) _Float16 Vl[128 * 64];     // [d][key], chunk-XOR swizzled

  // Q fragments (MFMA B operand, i8): lane (qd,ln) holds Q[r0+mh*16+ln][k=64ks2+qd*16..+15]
  int4v qa8[2][2];
  #pragma unroll
  for (int mh = 0; mh < 2; ++mh) {
    const signed char* qbase = qq + ((long)bh * S_LEN + r0 + mh * 16 + ln) * 128 + qd * 16;
    #pragma unroll
    for (int ks2 = 0; ks2 < 2; ++ks2)
      qa8[mh][ks2] = *(const int4v*)(qbase + ks2 * 64);
  }
  float qs = qscale[bh * 64 + (r0 >> 5)];

  float mrow[2];                            // running max (scaled log2 domain), q-row = ln
  floatx4 lacc[2];                          // l in C-layout rows qd*4+r (matches oacc)
  floatx4 oacc[2][8];
  #pragma unroll
  for (int mh = 0; mh < 2; ++mh) {
    mrow[mh] = -1e30f;
    #pragma unroll
    for (int r = 0; r < 4; ++r) lacc[mh][r] = 0.f;
    #pragma unroll
    for (int nd = 0; nd < 8; ++nd) oacc[mh][nd] = (floatx4){0.f,0.f,0.f,0.f};
  }

  int lo = q0 - wl; if (lo < 0) lo = 0;
  int hi = q0 + 127 + wr; if (hi > S_LEN - 1) hi = S_LEN - 1;
  int t_lo = lo >> 6, t_hi = hi >> 6;

  const float sm_scale2 = 0.08838834764831845f * 1.4426950408889634f;  // /sqrt(128)*log2e
  const signed char* kbase = kq + (long)bh * S_LEN * 128;
  const _Float16* vbase = vt + (long)bh * D_HEAD * S_LEN;
  const float* kscb = kscale + bh * 32;
  const half8 vones = { (_Float16)1, (_Float16)1, (_Float16)1, (_Float16)1,
                        (_Float16)1, (_Float16)1, (_Float16)1, (_Float16)1 };

  // register prefetch of first tile (same gc decomposition as the stores below)
  int4v kpre[2];
  half8 vpre[4];
  {
    int j0 = t_lo * 64;
    #pragma unroll
    for (int c = 0; c < 2; ++c) {
      int gc = t + c * 256;                // 512 chunks: 64 rows x 8 chunks of 16B
      kpre[c] = *(const int4v*)(kbase + (long)(j0 + (gc >> 3)) * 128 + (gc & 7) * 16);
    }
    #pragma unroll
    for (int c = 0; c < 4; ++c) {
      int gc = t + c * 256;                // 1024 chunks: 128 d-rows x 8 chunks of 8 halfs
      vpre[c] = *(const half8*)(vbase + (long)(gc >> 3) * S_LEN + j0 + (gc & 7) * 8);
    }
  }

  for (int tt = t_lo; tt <= t_hi; ++tt) {
    int j0 = tt * 64;
    __syncthreads();                       // prev tile's LDS reads done
    #pragma unroll
    for (int c = 0; c < 2; ++c) {          // K: row 0..63, 8 chunks of 16B; XOR by row
      int gc = t + c * 256;
      int row = gc >> 3, ci = gc & 7;
      int cs = (ci ^ row) & 7;
      *(int4v*)(Kl + row * 128 + cs * 16) = kpre[c];
    }
    #pragma unroll
    for (int c = 0; c < 4; ++c) {          // V: d-row 0..127, 8 chunks of 8 halfs
      int gc = t + c * 256;
      int row = gc >> 3, ci = gc & 7;
      int cs = (ci ^ row) & 7;
      *(half8*)(Vl + row * 64 + cs * 8) = vpre[c];
    }
    __syncthreads();
    if (tt < t_hi) {                       // issue next tile's global loads early
      int j1 = j0 + 64;
      #pragma unroll
      for (int c = 0; c < 2; ++c) {
        int gc = t + c * 256;
        kpre[c] = *(const int4v*)(kbase + (long)(j1 + (gc >> 3)) * 128 + (gc & 7) * 16);
      }
      #pragma unroll
      for (int c = 0; c < 4; ++c) {
        int gc = t + c * 256;
        vpre[c] = *(const half8*)(vbase + (long)(gc >> 3) * S_LEN + j1 + (gc & 7) * 8);
      }
    }

    // wave-uniform skip: tile outside this wave's 32-row window
    if (j0 + 63 < r0 - wl || j0 > r0 + 31 + wr) continue;

    float dscale2 = qs * kscb[tt] * sm_scale2;

    // S^T = K Q^T in int8: mfma_i32(A=K-frag, B=Q-frag). Lane (qd,ln) gets,
    // per nb, S[qrow=ln][key = nb*16 + qd*4 + r] in isacc[mh][nb][r] (int32).
    int4v isacc[2][4];
    #pragma unroll
    for (int mh = 0; mh < 2; ++mh)
      #pragma unroll
      for (int nb = 0; nb < 4; ++nb) isacc[mh][nb] = (int4v){0,0,0,0};
    #pragma unroll
    for (int nb = 0; nb < 4; ++nb)
      #pragma unroll
      for (int ks2 = 0; ks2 < 2; ++ks2) {
        int ci = ks2 * 4 + qd;             // logical 16B chunk = k-bytes ci*16..+15
        int cs = (ci ^ ln) & 7;
        int4v kf = *(const int4v*)(Kl + (nb * 16 + ln) * 128 + cs * 16);
        isacc[0][nb] = __builtin_amdgcn_mfma_i32_16x16x64_i8(kf, qa8[0][ks2], isacc[0][nb], 0, 0, 0);
        isacc[1][nb] = __builtin_amdgcn_mfma_i32_16x16x64_i8(kf, qa8[1][ks2], isacc[1][nb], 0, 0, 0);
      }

    // per-half: int-domain mask+max, exp2-domain softmax, defer-max,
    // in-register P pack into PV A-frags.
    half8 pa[2][2];
    #pragma unroll
    for (int mh = 0; mh < 2; ++mh) {
      int rb = r0 + mh * 16;
      bool need_mask = (j0 < rb + 15 - wl) || (j0 + 63 > rb + wr);
      int row = rb + ln;
      int mi[4][4];                        // [nb][r], masked int scores
      #pragma unroll
      for (int nb = 0; nb < 4; ++nb)
        #pragma unroll
        for (int r = 0; r < 4; ++r) {
          int s = isacc[mh][nb][r];
          if (need_mask) {
            int col = j0 + nb * 16 + qd * 4 + r;
            bool ok = (row - col <= wl) && (col - row <= wr);
            s = ok ? s : -1073741824;
          }
          mi[nb][r] = s;
        }
      int mxi = mi[0][0];
      #pragma unroll
      for (int nb = 0; nb < 4; ++nb)
        #pragma unroll
        for (int r = 0; r < 4; ++r) mxi = (mi[nb][r] > mxi) ? mi[nb][r] : mxi;
      {
        int o = __shfl_xor(mxi, 16, 64); mxi = (o > mxi) ? o : mxi;
        o = __shfl_xor(mxi, 32, 64);     mxi = (o > mxi) ? o : mxi;
      }
      float mx = (float)mxi * dscale2;

      if (__any(mx > mrow[mh] + 11.5f)) {  // defer-max (8*log2e in scaled domain)
        float mnew = fmaxf(mrow[mh], mx);
        float alpha = __builtin_amdgcn_exp2f(mrow[mh] - mnew);
        mrow[mh] = mnew;
        float ar[4];                       // alpha for C-layout rows qd*4+r
        #pragma unroll
        for (int r = 0; r < 4; ++r) ar[r] = __shfl(alpha, qd * 4 + r, 64);
        #pragma unroll
        for (int nd = 0; nd < 8; ++nd) {
          floatx4 o = oacc[mh][nd];
          #pragma unroll
          for (int r = 0; r < 4; ++r) o[r] *= ar[r];
          oacc[mh][nd] = o;
        }
        #pragma unroll
        for (int r = 0; r < 4; ++r) lacc[mh][r] *= ar[r];
      }

      float m0 = mrow[mh];
      // A-frag slot (ks, lane qd, j): j=0..3 -> key 32ks+qd*4+j ; j=4..7 -> +16
      #pragma unroll
      for (int ks = 0; ks < 2; ++ks) {
        half8 tf;
        #pragma unroll
        for (int r = 0; r < 4; ++r) {
          tf[r]     = (_Float16)__builtin_amdgcn_exp2f(fmaf((float)mi[2 * ks][r],     dscale2, -m0));
          tf[4 + r] = (_Float16)__builtin_amdgcn_exp2f(fmaf((float)mi[2 * ks + 1][r], dscale2, -m0));
        }
        pa[mh][ks] = tf;
      }
    }

    // O += P Vhat. V B-frag uses the SAME key permutation: slot (ks,qd,j) ->
    // key 32ks + 16*(j>>2) + qd*4 + (j&3): two b64 chunks at +0 and +16 keys.
    #pragma unroll
    for (int nd = 0; nd < 8; ++nd) {
      int rowv = nd * 16 + ln;
      #pragma unroll
      for (int ks = 0; ks < 2; ++ks) {
        int ci0 = ks * 4 + (qd >> 1);
        int o4 = (qd & 1) * 4;
        int cs0 = (ci0 ^ rowv) & 7;
        int cs1 = ((ci0 + 2) ^ rowv) & 7;
        half4 v0 = *(const half4*)(Vl + rowv * 64 + cs0 * 8 + o4);
        half4 v1 = *(const half4*)(Vl + rowv * 64 + cs1 * 8 + o4);
        half8 vf = { v0[0], v0[1], v0[2], v0[3], v1[0], v1[1], v1[2], v1[3] };
        oacc[0][nd] = __builtin_amdgcn_mfma_f32_16x16x32_f16(pa[0][ks], vf, oacc[0][nd], 0, 0, 0);
        oacc[1][nd] = __builtin_amdgcn_mfma_f32_16x16x32_f16(pa[1][ks], vf, oacc[1][nd], 0, 0, 0);
      }
    }
    #pragma unroll
    for (int mh = 0; mh < 2; ++mh) {
      lacc[mh] = __builtin_amdgcn_mfma_f32_16x16x32_f16(pa[mh][0], vones, lacc[mh], 0, 0, 0);
      lacc[mh] = __builtin_amdgcn_mfma_f32_16x16x32_f16(pa[mh][1], vones, lacc[mh], 0, 0, 0);
    }
  }

  // epilogue: out = fp16(O/l) + v_mean  (oacc/lacc rows = qd*4+r, cols = ln)
  float vm[8];
  #pragma unroll
  for (int nd = 0; nd < 8; ++nd)
    vm[nd] = vmean[bh * D_HEAD + nd * 16 + ln];
  float* obase = out + ((long)b * S_LEN) * NHID + h * D_HEAD;
  #pragma unroll
  for (int mh = 0; mh < 2; ++mh)
    #pragma unroll
    for (int r = 0; r < 4; ++r) {
      int row = r0 + mh * 16 + qd * 4 + r;
      float linv = 1.0f / lacc[mh][r];
      #pragma unroll
      for (int nd = 0; nd < 8; ++nd) {
        float o16 = (float)(_Float16)(oacc[mh][nd][r] * linv);
        obase[(long)row * NHID + nd * 16 + ln] = o16 + vm[nd];
      }
    }
}

extern "C" void kernel_launch(void* const* d_in, const int* in_sizes, int n_in,
                              void* d_out, int out_size, void* d_ws, size_t ws_size,
                              hipStream_t stream) {
  (void)in_sizes; (void)n_in; (void)out_size; (void)ws_size;
  const float* q = (const float*)d_in[0];
  const float* k = (const float*)d_in[1];
  const float* v = (const float*)d_in[2];
  const int* wl = (const int*)d_in[3];
  const int* wr = (const int*)d_in[4];
  float* out = (float*)d_out;

  char* ws = (char*)d_ws;
  size_t off = 0;
  const size_t i8sz = (size_t)N_BH * S_LEN * D_HEAD;                      // 8.39 MB
  const size_t f16sz = (size_t)N_BH * S_LEN * D_HEAD * sizeof(_Float16); // 16.78 MB
  signed char* qq = (signed char*)(ws + off); off += i8sz;
  signed char* kq = (signed char*)(ws + off); off += i8sz;
  _Float16* vt = (_Float16*)(ws + off); off += f16sz;
  float* ksumP  = (float*)(ws + off); off += (size_t)N_BH * 32 * 128 * sizeof(float);
  float* vsumP  = (float*)(ws + off); off += (size_t)N_BH * 32 * 128 * sizeof(float);
  float* vmean  = (float*)(ws + off); off += N_BH * D_HEAD * sizeof(float);
  float* qscale = (float*)(ws + off); off += N_BH * 64 * sizeof(float);
  float* kscale = (float*)(ws + off); off += N_BH * 32 * sizeof(float);

  means_kernel<<<1024, 256, 0, stream>>>(k, v, ksumP, vsumP);
  prep_kernel<<<4096, 256, 0, stream>>>(q, k, v, ksumP, vsumP, qq, kq, vt, qscale, kscale, vmean);
  attn_kernel<<<512, 256, 0, stream>>>(qq, kq, vt, qscale, kscale, vmean, wl, wr, out);
}

// Round 9
// 221.328 us; speedup vs baseline: 3.7184x; 1.0082x over previous
//
#include <hip/hip_runtime.h>
#include <hip/hip_fp16.h>
#include <math.h>

#define S_LEN 2048
#define NHID  2048
#define D_HEAD 128
#define N_BH  32
#define EPS_Q 1e-8f

typedef _Float16 half8 __attribute__((ext_vector_type(8)));
typedef _Float16 half4 __attribute__((ext_vector_type(4)));
typedef float floatx4 __attribute__((ext_vector_type(4)));
typedef int int4v __attribute__((ext_vector_type(4)));

// ---------------- kernel 1: means partials + Q quant (independent work fused) ----------------
__global__ void mq_kernel(const float* __restrict__ kk, const float* __restrict__ vv,
                          const float* __restrict__ q,
                          float* __restrict__ ksumP, float* __restrict__ vsumP,
                          signed char* __restrict__ qq, float* __restrict__ qscale) {
  int blk = blockIdx.x;
  int t = threadIdx.x;
  int d4 = t & 31, sg = t >> 5;
  __shared__ floatx4 red[256];
  __shared__ float wred[4];

  if (blk < 1024) {
    // ---- means partials: 32 bh * 32 chunks of 64 rows
    int bh = blk >> 5, chunk = blk & 31;
    int b = bh >> 4, h = bh & 15;
    int s0 = chunk * 64;
    const long base = ((long)(b * S_LEN + s0)) * NHID + h * D_HEAD + d4 * 4;
    floatx4 ks = {0.f,0.f,0.f,0.f}, vs = {0.f,0.f,0.f,0.f};
    #pragma unroll
    for (int j = 0; j < 8; ++j) {
      long idx = base + (long)(sg * 8 + j) * NHID;
      ks += *(const floatx4*)(kk + idx);
      vs += *(const floatx4*)(vv + idx);
    }
    red[t] = ks; __syncthreads();
    if (t < 128) red[t] += red[t + 128]; __syncthreads();
    if (t < 64)  red[t] += red[t + 64];  __syncthreads();
    if (t < 32) *(floatx4*)(ksumP + (long)blk * 128 + t * 4) = red[t] + red[t + 32];
    __syncthreads();
    red[t] = vs; __syncthreads();
    if (t < 128) red[t] += red[t + 128]; __syncthreads();
    if (t < 64)  red[t] += red[t + 64];  __syncthreads();
    if (t < 32) *(floatx4*)(vsumP + (long)blk * 128 + t * 4) = red[t] + red[t + 32];
  } else {
    // ---- Q quant: 32 rows x 128 d -> packed int8
    int bb = blk - 1024;
    int bh = bb >> 6, g = bb & 63;
    int b = bh >> 4, h = bh & 15;
    int s0 = g * 32;
    int lane = t & 63, wid = t >> 6;
    const long gbase = ((long)(b * S_LEN + s0)) * NHID + h * D_HEAD + d4 * 4;
    floatx4 vals[4]; float am = 0.f;
    #pragma unroll
    for (int j = 0; j < 4; ++j) {
      floatx4 x = *(const floatx4*)(q + gbase + (long)(sg + j * 8) * NHID);
      vals[j] = x;
      am = fmaxf(am, fmaxf(fmaxf(fabsf(x[0]), fabsf(x[1])), fmaxf(fabsf(x[2]), fabsf(x[3]))));
    }
    #pragma unroll
    for (int off = 1; off < 64; off <<= 1) am = fmaxf(am, __shfl_xor(am, off, 64));
    if (lane == 0) wred[wid] = am;
    __syncthreads();
    am = fmaxf(fmaxf(wred[0], wred[1]), fmaxf(wred[2], wred[3]));
    float scale = fmaxf(am / 127.0f, EPS_Q);
    if (t == 0) qscale[bh * 64 + g] = scale;
    float inv = 1.0f / scale;
    #pragma unroll
    for (int j = 0; j < 4; ++j) {
      int pk = 0;
      #pragma unroll
      for (int c = 0; c < 4; ++c) {
        int qv = (int)fminf(fmaxf(rintf(vals[j][c] * inv), -127.f), 127.f);
        pk |= (qv & 255) << (8 * c);
      }
      ((int*)qq)[((long)bh * S_LEN + s0 + sg + j * 8) * 32 + d4] = pk;
    }
  }
}

// ---------------- kernel 2: K smooth+quant | V smooth+transpose (sigma-permuted) ----------------
__global__ void kv_kernel(const float* __restrict__ k, const float* __restrict__ v,
                          const float* __restrict__ ksumP, const float* __restrict__ vsumP,
                          signed char* __restrict__ kq, _Float16* __restrict__ vt,
                          float* __restrict__ kscale, float* __restrict__ vmean) {
  int blk = blockIdx.x;
  int t = threadIdx.x;
  int lane = t & 63, wid = t >> 6;
  __shared__ float wred[4];
  __shared__ __align__(16) _Float16 tile[64 * 136];
  int d4 = t & 31, sg = t >> 5;

  if (blk < 1024) {
    // ---- K smooth+quant: 64 rows x 128 d -> packed int8
    int bh = blk >> 5, g = blk & 31;
    int b = bh >> 4, h = bh & 15;
    int s0 = g * 64;
    floatx4 msum = {0.f,0.f,0.f,0.f};
    #pragma unroll
    for (int c = 0; c < 32; ++c)
      msum += *(const floatx4*)(ksumP + (long)(bh * 32 + c) * 128 + d4 * 4);
    floatx4 mean = msum * (1.0f / 2048.0f);
    const long gbase = ((long)(b * S_LEN + s0)) * NHID + h * D_HEAD + d4 * 4;
    floatx4 vals[8]; float am = 0.f;
    #pragma unroll
    for (int j = 0; j < 8; ++j) {
      floatx4 x = *(const floatx4*)(k + gbase + (long)(sg + j * 8) * NHID) - mean;
      vals[j] = x;
      am = fmaxf(am, fmaxf(fmaxf(fabsf(x[0]), fabsf(x[1])), fmaxf(fabsf(x[2]), fabsf(x[3]))));
    }
    #pragma unroll
    for (int off = 1; off < 64; off <<= 1) am = fmaxf(am, __shfl_xor(am, off, 64));
    if (lane == 0) wred[wid] = am;
    __syncthreads();
    am = fmaxf(fmaxf(wred[0], wred[1]), fmaxf(wred[2], wred[3]));
    float scale = fmaxf(am / 127.0f, EPS_Q);
    if (t == 0) kscale[bh * 32 + g] = scale;
    float inv = 1.0f / scale;
    #pragma unroll
    for (int j = 0; j < 8; ++j) {
      int pk = 0;
      #pragma unroll
      for (int c = 0; c < 4; ++c) {
        int qv = (int)fminf(fmaxf(rintf(vals[j][c] * inv), -127.f), 127.f);
        pk |= (qv & 255) << (8 * c);
      }
      ((int*)kq)[((long)bh * S_LEN + s0 + sg + j * 8) * 32 + d4] = pk;
    }
  } else {
    // ---- V smooth -> fp16 transpose to [bh][d][s], key axis sigma-permuted
    // within each 32-key group so attn's PV B-frag is one contiguous b128:
    // stored column c holds key (c&32) | sigma(c&31),
    // sigma(qd*8+j) = qd*4 + j + (j>=4 ? 12 : 0).
    int bb = blk - 1024;
    int bh = bb >> 5, st = bb & 31;
    int b = bh >> 4, h = bh & 15;
    int s0 = st * 64;
    floatx4 msum = {0.f,0.f,0.f,0.f};
    #pragma unroll
    for (int c = 0; c < 32; ++c)
      msum += *(const floatx4*)(vsumP + (long)(bh * 32 + c) * 128 + d4 * 4);
    floatx4 mean = msum * (1.0f / 2048.0f);
    if (st == 0 && sg == 0)
      *(floatx4*)(vmean + bh * D_HEAD + d4 * 4) = mean;
    const long gbase = ((long)(b * S_LEN + s0)) * NHID + h * D_HEAD + d4 * 4;
    #pragma unroll
    for (int j = 0; j < 8; ++j) {
      floatx4 x = *(const floatx4*)(v + gbase + (long)(sg + j * 8) * NHID) - mean;
      half4 hv = { (_Float16)x[0], (_Float16)x[1], (_Float16)x[2], (_Float16)x[3] };
      *(half4*)(tile + (sg + j * 8) * 136 + d4 * 4) = hv;
    }
    __syncthreads();
    int dr = t >> 1, sh = (t & 1) * 32;
    _Float16* dst = vt + ((long)bh * D_HEAD + dr) * S_LEN + s0 + sh;
    #pragma unroll
    for (int jo = 0; jo < 4; ++jo) {
      union { half8 v8; _Float16 h[8]; } u;
      #pragma unroll
      for (int ji = 0; ji < 8; ++ji) {
        int key = jo * 4 + ji + (ji >= 4 ? 12 : 0);   // sigma within 32-key group
        u.h[ji] = tile[(sh + key) * 136 + dr];
      }
      *(half8*)(dst + jo * 8) = u.v8;
    }
  }
}

// ---------------- kernel 3: fused sliding-window attention ----------------
// v10 = v9 (i8 QK + int-max/exp2 softmax, 87.5us) with V pre-permuted in vt
// so each PV B-fragment is ONE ds_read_b128 (was 2x b64 16 keys apart):
// V LDS reads 32 -> 16 per wave-tile, -30% DS issue slots (R8's largest
// pipe at ~50% busy by instruction arithmetic). P-pack unchanged (the
// permutation equals the A-frag slot map already in use).
// (256,2): R3-R5 proved higher waves/EU requests spill this datapath.
__launch_bounds__(256, 2)
__global__ void attn_kernel(const signed char* __restrict__ qq, const signed char* __restrict__ kq,
                            const _Float16* __restrict__ vt,
                            const float* __restrict__ qscale, const float* __restrict__ kscale,
                            const float* __restrict__ vmean,
                            const int* __restrict__ wlp, const int* __restrict__ wrp,
                            float* __restrict__ out) {
  int bid = blockIdx.x;
  int xcd = bid & 7, rest = bid >> 3;
  int bh = xcd * 4 + (rest & 3);
  int qb = rest >> 2;
  int b = bh >> 4, h = bh & 15;
  int q0 = qb * 128;

  int wl = *wlp; if (wl < 0) wl = S_LEN;
  int wr = *wrp; if (wr < 0) wr = S_LEN;

  int t = threadIdx.x;
  int wv = t >> 6;
  int lane = t & 63;
  int ln = lane & 15;
  int qd = lane >> 4;

  int r0 = q0 + wv * 32;                   // this wave's 32 q rows

  __shared__ __align__(16) signed char Kl[64 * 128];  // [key][k-byte], 8x16B chunks XOR swz
  __shared__ __align__(16) _Float16 Vl[128 * 64];     // [d][key'], sigma-permuted, XOR swz

  // Q fragments (MFMA B operand, i8): lane (qd,ln) holds Q[r0+mh*16+ln][k=64ks2+qd*16..+15]
  int4v qa8[2][2];
  #pragma unroll
  for (int mh = 0; mh < 2; ++mh) {
    const signed char* qbase = qq + ((long)bh * S_LEN + r0 + mh * 16 + ln) * 128 + qd * 16;
    #pragma unroll
    for (int ks2 = 0; ks2 < 2; ++ks2)
      qa8[mh][ks2] = *(const int4v*)(qbase + ks2 * 64);
  }
  float qs = qscale[bh * 64 + (r0 >> 5)];

  float mrow[2];                            // running max (scaled log2 domain), q-row = ln
  floatx4 lacc[2];                          // l in C-layout rows qd*4+r (matches oacc)
  floatx4 oacc[2][8];
  #pragma unroll
  for (int mh = 0; mh < 2; ++mh) {
    mrow[mh] = -1e30f;
    #pragma unroll
    for (int r = 0; r < 4; ++r) lacc[mh][r] = 0.f;
    #pragma unroll
    for (int nd = 0; nd < 8; ++nd) oacc[mh][nd] = (floatx4){0.f,0.f,0.f,0.f};
  }

  int lo = q0 - wl; if (lo < 0) lo = 0;
  int hi = q0 + 127 + wr; if (hi > S_LEN - 1) hi = S_LEN - 1;
  int t_lo = lo >> 6, t_hi = hi >> 6;

  const float sm_scale2 = 0.08838834764831845f * 1.4426950408889634f;  // /sqrt(128)*log2e
  const signed char* kbase = kq + (long)bh * S_LEN * 128;
  const _Float16* vbase = vt + (long)bh * D_HEAD * S_LEN;
  const float* kscb = kscale + bh * 32;
  const half8 vones = { (_Float16)1, (_Float16)1, (_Float16)1, (_Float16)1,
                        (_Float16)1, (_Float16)1, (_Float16)1, (_Float16)1 };

  // register prefetch of first tile (same gc decomposition as the stores below)
  int4v kpre[2];
  half8 vpre[4];
  {
    int j0 = t_lo * 64;
    #pragma unroll
    for (int c = 0; c < 2; ++c) {
      int gc = t + c * 256;                // 512 chunks: 64 rows x 8 chunks of 16B
      kpre[c] = *(const int4v*)(kbase + (long)(j0 + (gc >> 3)) * 128 + (gc & 7) * 16);
    }
    #pragma unroll
    for (int c = 0; c < 4; ++c) {
      int gc = t + c * 256;                // 1024 chunks: 128 d-rows x 8 chunks of 8 halfs
      vpre[c] = *(const half8*)(vbase + (long)(gc >> 3) * S_LEN + j0 + (gc & 7) * 8);
    }
  }

  for (int tt = t_lo; tt <= t_hi; ++tt) {
    int j0 = tt * 64;
    __syncthreads();                       // prev tile's LDS reads done
    #pragma unroll
    for (int c = 0; c < 2; ++c) {          // K: row 0..63, 8 chunks of 16B; XOR by row
      int gc = t + c * 256;
      int row = gc >> 3, ci = gc & 7;
      int cs = (ci ^ row) & 7;
      *(int4v*)(Kl + row * 128 + cs * 16) = kpre[c];
    }
    #pragma unroll
    for (int c = 0; c < 4; ++c) {          // V: d-row 0..127, 8 chunks of 8 halfs
      int gc = t + c * 256;
      int row = gc >> 3, ci = gc & 7;
      int cs = (ci ^ row) & 7;
      *(half8*)(Vl + row * 64 + cs * 8) = vpre[c];
    }
    __syncthreads();
    if (tt < t_hi) {                       // issue next tile's global loads early
      int j1 = j0 + 64;
      #pragma unroll
      for (int c = 0; c < 2; ++c) {
        int gc = t + c * 256;
        kpre[c] = *(const int4v*)(kbase + (long)(j1 + (gc >> 3)) * 128 + (gc & 7) * 16);
      }
      #pragma unroll
      for (int c = 0; c < 4; ++c) {
        int gc = t + c * 256;
        vpre[c] = *(const half8*)(vbase + (long)(gc >> 3) * S_LEN + j1 + (gc & 7) * 8);
      }
    }

    // wave-uniform skip: tile outside this wave's 32-row window
    if (j0 + 63 < r0 - wl || j0 > r0 + 31 + wr) continue;

    float dscale2 = qs * kscb[tt] * sm_scale2;

    // S^T = K Q^T in int8: mfma_i32(A=K-frag, B=Q-frag). Lane (qd,ln) gets,
    // per nb, S[qrow=ln][key = nb*16 + qd*4 + r] in isacc[mh][nb][r] (int32).
    int4v isacc[2][4];
    #pragma unroll
    for (int mh = 0; mh < 2; ++mh)
      #pragma unroll
      for (int nb = 0; nb < 4; ++nb) isacc[mh][nb] = (int4v){0,0,0,0};
    #pragma unroll
    for (int nb = 0; nb < 4; ++nb)
      #pragma unroll
      for (int ks2 = 0; ks2 < 2; ++ks2) {
        int ci = ks2 * 4 + qd;             // logical 16B chunk = k-bytes ci*16..+15
        int cs = (ci ^ ln) & 7;
        int4v kf = *(const int4v*)(Kl + (nb * 16 + ln) * 128 + cs * 16);
        isacc[0][nb] = __builtin_amdgcn_mfma_i32_16x16x64_i8(kf, qa8[0][ks2], isacc[0][nb], 0, 0, 0);
        isacc[1][nb] = __builtin_amdgcn_mfma_i32_16x16x64_i8(kf, qa8[1][ks2], isacc[1][nb], 0, 0, 0);
      }

    // per-half: int-domain mask+max, exp2-domain softmax, defer-max,
    // in-register P pack into PV A-frags.
    half8 pa[2][2];
    #pragma unroll
    for (int mh = 0; mh < 2; ++mh) {
      int rb = r0 + mh * 16;
      bool need_mask = (j0 < rb + 15 - wl) || (j0 + 63 > rb + wr);
      int row = rb + ln;
      int mi[4][4];                        // [nb][r], masked int scores
      #pragma unroll
      for (int nb = 0; nb < 4; ++nb)
        #pragma unroll
        for (int r = 0; r < 4; ++r) {
          int s = isacc[mh][nb][r];
          if (need_mask) {
            int col = j0 + nb * 16 + qd * 4 + r;
            bool ok = (row - col <= wl) && (col - row <= wr);
            s = ok ? s : -1073741824;
          }
          mi[nb][r] = s;
        }
      int mxi = mi[0][0];
      #pragma unroll
      for (int nb = 0; nb < 4; ++nb)
        #pragma unroll
        for (int r = 0; r < 4; ++r) mxi = (mi[nb][r] > mxi) ? mi[nb][r] : mxi;
      {
        int o = __shfl_xor(mxi, 16, 64); mxi = (o > mxi) ? o : mxi;
        o = __shfl_xor(mxi, 32, 64);     mxi = (o > mxi) ? o : mxi;
      }
      float mx = (float)mxi * dscale2;

      if (__any(mx > mrow[mh] + 11.5f)) {  // defer-max (8*log2e in scaled domain)
        float mnew = fmaxf(mrow[mh], mx);
        float alpha = __builtin_amdgcn_exp2f(mrow[mh] - mnew);
        mrow[mh] = mnew;
        float ar[4];                       // alpha for C-layout rows qd*4+r
        #pragma unroll
        for (int r = 0; r < 4; ++r) ar[r] = __shfl(alpha, qd * 4 + r, 64);
        #pragma unroll
        for (int nd = 0; nd < 8; ++nd) {
          floatx4 o = oacc[mh][nd];
          #pragma unroll
          for (int r = 0; r < 4; ++r) o[r] *= ar[r];
          oacc[mh][nd] = o;
        }
        #pragma unroll
        for (int r = 0; r < 4; ++r) lacc[mh][r] *= ar[r];
      }

      float m0 = mrow[mh];
      // A-frag slot (ks, lane qd, j): j=0..3 -> key 32ks+qd*4+j ; j=4..7 -> +16
      #pragma unroll
      for (int ks = 0; ks < 2; ++ks) {
        half8 tf;
        #pragma unroll
        for (int r = 0; r < 4; ++r) {
          tf[r]     = (_Float16)__builtin_amdgcn_exp2f(fmaf((float)mi[2 * ks][r],     dscale2, -m0));
          tf[4 + r] = (_Float16)__builtin_amdgcn_exp2f(fmaf((float)mi[2 * ks + 1][r], dscale2, -m0));
        }
        pa[mh][ks] = tf;
      }
    }

    // O += P Vhat. V is sigma-permuted in LDS, so each B-frag is ONE b128:
    // chunk ci = ks*4 + qd of row rowv (XOR-swizzled).
    #pragma unroll
    for (int nd = 0; nd < 8; ++nd) {
      int rowv = nd * 16 + ln;
      #pragma unroll
      for (int ks = 0; ks < 2; ++ks) {
        int ci = ks * 4 + qd;
        int cs = (ci ^ rowv) & 7;
        half8 vf = *(const half8*)(Vl + rowv * 64 + cs * 8);
        oacc[0][nd] = __builtin_amdgcn_mfma_f32_16x16x32_f16(pa[0][ks], vf, oacc[0][nd], 0, 0, 0);
        oacc[1][nd] = __builtin_amdgcn_mfma_f32_16x16x32_f16(pa[1][ks], vf, oacc[1][nd], 0, 0, 0);
      }
    }
    #pragma unroll
    for (int mh = 0; mh < 2; ++mh) {
      lacc[mh] = __builtin_amdgcn_mfma_f32_16x16x32_f16(pa[mh][0], vones, lacc[mh], 0, 0, 0);
      lacc[mh] = __builtin_amdgcn_mfma_f32_16x16x32_f16(pa[mh][1], vones, lacc[mh], 0, 0, 0);
    }
  }

  // epilogue: out = fp16(O/l) + v_mean  (oacc/lacc rows = qd*4+r, cols = ln)
  float vm[8];
  #pragma unroll
  for (int nd = 0; nd < 8; ++nd)
    vm[nd] = vmean[bh * D_HEAD + nd * 16 + ln];
  float* obase = out + ((long)b * S_LEN) * NHID + h * D_HEAD;
  #pragma unroll
  for (int mh = 0; mh < 2; ++mh)
    #pragma unroll
    for (int r = 0; r < 4; ++r) {
      int row = r0 + mh * 16 + qd * 4 + r;
      float linv = 1.0f / lacc[mh][r];
      #pragma unroll
      for (int nd = 0; nd < 8; ++nd) {
        float o16 = (float)(_Float16)(oacc[mh][nd][r] * linv);
        obase[(long)row * NHID + nd * 16 + ln] = o16 + vm[nd];
      }
    }
}

extern "C" void kernel_launch(void* const* d_in, const int* in_sizes, int n_in,
                              void* d_out, int out_size, void* d_ws, size_t ws_size,
                              hipStream_t stream) {
  (void)in_sizes; (void)n_in; (void)out_size; (void)ws_size;
  const float* q = (const float*)d_in[0];
  const float* k = (const float*)d_in[1];
  const float* v = (const float*)d_in[2];
  const int* wl = (const int*)d_in[3];
  const int* wr = (const int*)d_in[4];
  float* out = (float*)d_out;

  char* ws = (char*)d_ws;
  size_t off = 0;
  const size_t i8sz = (size_t)N_BH * S_LEN * D_HEAD;                      // 8.39 MB
  const size_t f16sz = (size_t)N_BH * S_LEN * D_HEAD * sizeof(_Float16); // 16.78 MB
  signed char* qq = (signed char*)(ws + off); off += i8sz;
  signed char* kq = (signed char*)(ws + off); off += i8sz;
  _Float16* vt = (_Float16*)(ws + off); off += f16sz;
  float* ksumP  = (float*)(ws + off); off += (size_t)N_BH * 32 * 128 * sizeof(float);
  float* vsumP  = (float*)(ws + off); off += (size_t)N_BH * 32 * 128 * sizeof(float);
  float* vmean  = (float*)(ws + off); off += N_BH * D_HEAD * sizeof(float);
  float* qscale = (float*)(ws + off); off += N_BH * 64 * sizeof(float);
  float* kscale = (float*)(ws + off); off += N_BH * 32 * sizeof(float);

  mq_kernel<<<3072, 256, 0, stream>>>(k, v, q, ksumP, vsumP, qq, qscale);
  kv_kernel<<<2048, 256, 0, stream>>>(k, v, ksumP, vsumP, kq, vt, kscale, vmean);
  attn_kernel<<<512, 256, 0, stream>>>(qq, kq, vt, qscale, kscale, vmean, wl, wr, out);
}